// Round 1
// baseline (709.066 us; speedup 1.0000x reference)
//
#include <hip/hip_runtime.h>
#include <math.h>

#define NATOMS 16384
#define NEDGES 524288
#define NLAYERS 4
#define TE 64      // edges per block in msg kernel

typedef __bf16 bf16x8 __attribute__((ext_vector_type(8)));
typedef __bf16 bf16x4 __attribute__((ext_vector_type(4)));
typedef __bf16 bf16x2 __attribute__((ext_vector_type(2)));
typedef float f32x4 __attribute__((ext_vector_type(4)));

// fast silu: x * rcp(1+exp(-x))
__device__ __forceinline__ float silu_f(float x) {
  return x * __builtin_amdgcn_rcpf(1.0f + __expf(-x));
}

// ---------------- CSR preprocessing ----------------
__global__ __launch_bounds__(1024) void scan_kernel(
    const int* __restrict__ counts, int* __restrict__ cursor,
    float* __restrict__ degf)
{
  __shared__ int s_tot[1024];
  int tid = threadIdx.x;
  int v[16];
  {
    const int4* cp = (const int4*)(counts + tid * 16);
    int4 a = cp[0], b = cp[1], c = cp[2], d = cp[3];
    v[0]=a.x; v[1]=a.y; v[2]=a.z; v[3]=a.w;
    v[4]=b.x; v[5]=b.y; v[6]=b.z; v[7]=b.w;
    v[8]=c.x; v[9]=c.y; v[10]=c.z; v[11]=c.w;
    v[12]=d.x; v[13]=d.y; v[14]=d.z; v[15]=d.w;
  }
  int tot = 0;
  #pragma unroll
  for (int i = 0; i < 16; i++) tot += v[i];
  s_tot[tid] = tot;
  __syncthreads();
  for (int off = 1; off < 1024; off <<= 1) {
    int t = (tid >= off) ? s_tot[tid - off] : 0;
    __syncthreads();
    s_tot[tid] += t;
    __syncthreads();
  }
  int run = s_tot[tid] - tot;   // exclusive prefix
  #pragma unroll
  for (int i = 0; i < 16; i++) {
    cursor[tid * 16 + i] = run;
    degf[tid * 16 + i] = (float)v[i];
    run += v[i];
  }
}

// scatter + RBF fused: each edge computes its sorted slot p, writes esrc/edst
// AND its RBF features directly to efb[p].
__global__ __launch_bounds__(256) void scatter_rbf_kernel(
    const int* __restrict__ src, const int* __restrict__ dst,
    int* __restrict__ cursor, const float* __restrict__ pos,
    int* __restrict__ esrc, int* __restrict__ edst,
    __bf16* __restrict__ efb)
{
  int e = blockIdx.x * 256 + threadIdx.x;
  int s = src[e], d = dst[e];
  int p = atomicAdd(&cursor[d], 1);
  esrc[p] = s;
  edst[p] = d;
  float dx = pos[d * 3 + 0] - pos[s * 3 + 0];
  float dy = pos[d * 3 + 1] - pos[s * 3 + 1];
  float dz = pos[d * 3 + 2] - pos[s * 3 + 2];
  float dist = sqrtf(dx * dx + dy * dy + dz * dz + 1e-12f);
  float env = (dist < 10.0f)
                  ? 0.5f * (cosf(3.14159265358979f * dist * 0.1f) + 1.0f)
                  : 0.0f;
  bf16x8 o0, o1;
  #pragma unroll
  for (int i = 0; i < 16; i++) {
    float c = (10.0f / 15.0f) * (float)i;
    float t = dist - c;
    float v = env * __expf(-t * t * 1.28f);
    if (i < 8) o0[i] = (__bf16)v; else o1[i - 8] = (__bf16)v;
  }
  *(bf16x8*)(efb + (size_t)p * 16 + 0) = o0;
  *(bf16x8*)(efb + (size_t)p * 16 + 8) = o1;
}

// ---------------- merged front kernel: weight prep + dst histogram + embed ----------------
#define NB_PREP (801 * NLAYERS)
#define NB_HIST (NEDGES / 256)
#define NB_EMB  (NATOMS / 2)

__global__ __launch_bounds__(256) void front_kernel(
    const float* __restrict__ mW1, const float* __restrict__ mW2,
    const float* __restrict__ uW1, const float* __restrict__ uW2,
    const float* __restrict__ mb2,
    __bf16* __restrict__ W1at, __bf16* __restrict__ W1bt,
    __bf16* __restrict__ B2c, __bf16* __restrict__ uW1ft,
    __bf16* __restrict__ uW2t, float* __restrict__ b2u,
    const int* __restrict__ dstI, int* __restrict__ counts,
    const float* __restrict__ x, const float* __restrict__ eW1,
    const float* __restrict__ eb1, const float* __restrict__ eW2,
    const float* __restrict__ eb2, float* __restrict__ h,
    __bf16* __restrict__ hb)
{
  __shared__ float xs[2][26];
  __shared__ float hid[2][132];
  int bxf = blockIdx.x, tid = threadIdx.x;

  if (bxf < NB_PREP) {
    long l = bxf / 801;
    int bx = bxf - (int)l * 801;
    if (bx < 128) {
      int i = bx * 256 + tid;              // 256*128
      int n = i >> 7, k = i & 127;
      W1at[l * (256L * 128) + i] = (__bf16)mW1[l * (272L * 256) + (size_t)k * 256 + n];
    } else if (bx < 256) {
      int i = (bx - 128) * 256 + tid;
      int n = i >> 7, k = i & 127;
      W1bt[l * (256L * 128) + i] = (__bf16)mW1[l * (272L * 256) + (size_t)(128 + k) * 256 + n];
    } else if (bx < 288) {
      int i = (bx - 256) * 256 + tid;      // 256*32
      int c = i >> 5, k = i & 31;
      float v = (k < 16) ? mW1[l * (272L * 256) + (size_t)(256 + k) * 256 + c] : 0.0f;
      B2c[l * (256L * 32) + i] = (__bf16)v;
    } else if (bx < 672) {
      // block = one k (384 per layer), threads = n: coalesced reads, scalar mW2
      int k = bx - 288;                    // 0..383
      int n = tid;                         // 0..255
      float v;
      if (k < 128) {
        v = uW1[l * 65536 + (size_t)k * 256 + n];
      } else {
        int r = k - 128;
        v = 0.0f;
        for (int j = 0; j < 128; j++)
          v += mW2[(l * 256 + r) * 128 + j] * uW1[l * 65536 + (size_t)(128 + j) * 256 + n];
      }
      uW1ft[l * (256L * 384) + (size_t)n * 384 + k] = (__bf16)v;
    } else if (bx < 800) {
      int i = (bx - 672) * 256 + tid;      // 128*256
      int n = i >> 8, k = i & 255;
      uW2t[l * (128L * 256) + i] = (__bf16)uW2[l * (256L * 128) + (size_t)k * 128 + n];
    } else {
      int c = tid;
      float acc = 0.0f;
      for (int j = 0; j < 128; j++)
        acc += mb2[l * 128 + j] * uW1[l * 65536 + (size_t)(128 + j) * 256 + c];
      b2u[l * 256 + c] = acc;
    }
  } else if (bxf < NB_PREP + NB_HIST) {
    int e = (bxf - NB_PREP) * 256 + tid;
    atomicAdd(&counts[dstI[e]], 1);
  } else {
    int nb = bxf - (NB_PREP + NB_HIST);
    int hf = tid >> 7, j = tid & 127;
    int n = nb * 2 + hf;
    if (j < 26) xs[hf][j] = x[(size_t)n * 26 + j];
    __syncthreads();
    float acc = eb1[j];
    #pragma unroll
    for (int k = 0; k < 26; k++) acc += xs[hf][k] * eW1[k * 128 + j];
    hid[hf][j] = silu_f(acc);
    __syncthreads();
    float acc2 = eb2[j];
    #pragma unroll 8
    for (int k = 0; k < 128; k++) acc2 += hid[hf][k] * eW2[k * 128 + j];
    h[(size_t)n * 128 + j] = acc2;
    hb[(size_t)n * 128 + j] = (__bf16)acc2;
  }
}

// ---------------- zprep (layer 0 only): z1b, z2b; zeros aggH ----------------
__global__ __launch_bounds__(256) void zprep_kernel(
    const __bf16* __restrict__ hb, const float* __restrict__ b1,
    const __bf16* __restrict__ W1at, const __bf16* __restrict__ W1bt,
    __bf16* __restrict__ z1b, __bf16* __restrict__ z2b, float* __restrict__ aggH)
{
  __shared__ __bf16 s_n[64][136];
  int tid = threadIdx.x, n0 = blockIdx.x * 64;
  {
    int n = tid >> 2, t4 = tid & 3;
    const bf16x8* hr = (const bf16x8*)(hb + (size_t)(n0 + n) * 128);
    #pragma unroll
    for (int i = 0; i < 4; i++)
      *(bf16x8*)&s_n[n][t4 * 8 + 32 * i] = hr[t4 + 4 * i];
  }
  {
    float4 zz = make_float4(0.f, 0.f, 0.f, 0.f);
    float4* ap = (float4*)(aggH + (size_t)n0 * 256);
    for (int i = tid; i < 64 * 256 / 4; i += 256) ap[i] = zz;
  }
  __syncthreads();
  const int wv = tid >> 6, ln = tid & 63, lc = ln & 15, qd = ln >> 4;
  for (int cp = 0; cp < 2; cp++) {
    f32x4 aA[4][2], aB[4][2];
    #pragma unroll
    for (int nt = 0; nt < 2; nt++) {
      float bv = b1[cp * 128 + wv * 32 + nt * 16 + lc];
      #pragma unroll
      for (int mt = 0; mt < 4; mt++) {
        aA[mt][nt][0] = 0.f; aA[mt][nt][1] = 0.f;
        aA[mt][nt][2] = 0.f; aA[mt][nt][3] = 0.f;
        aB[mt][nt][0] = bv; aB[mt][nt][1] = bv;
        aB[mt][nt][2] = bv; aB[mt][nt][3] = bv;
      }
    }
    #pragma unroll
    for (int kt = 0; kt < 4; kt++) {
      bf16x8 af[4];
      #pragma unroll
      for (int mt = 0; mt < 4; mt++)
        af[mt] = *(const bf16x8*)&s_n[mt * 16 + lc][kt * 32 + qd * 8];
      bf16x8 bwA[2], bwB[2];
      #pragma unroll
      for (int nt = 0; nt < 2; nt++) {
        int c = cp * 128 + wv * 32 + nt * 16 + lc;
        bwA[nt] = *(const bf16x8*)(W1at + (size_t)c * 128 + kt * 32 + qd * 8);
        bwB[nt] = *(const bf16x8*)(W1bt + (size_t)c * 128 + kt * 32 + qd * 8);
      }
      #pragma unroll
      for (int mt = 0; mt < 4; mt++)
        #pragma unroll
        for (int nt = 0; nt < 2; nt++) {
          aA[mt][nt] = __builtin_amdgcn_mfma_f32_16x16x32_bf16(af[mt], bwA[nt], aA[mt][nt], 0, 0, 0);
          aB[mt][nt] = __builtin_amdgcn_mfma_f32_16x16x32_bf16(af[mt], bwB[nt], aB[mt][nt], 0, 0, 0);
        }
    }
    #pragma unroll
    for (int mt = 0; mt < 4; mt++)
      #pragma unroll
      for (int nt = 0; nt < 2; nt++) {
        int c = cp * 128 + wv * 32 + nt * 16 + lc;
        #pragma unroll
        for (int r = 0; r < 4; r++) {
          int n = n0 + mt * 16 + qd * 4 + r;
          z1b[(size_t)n * 256 + c] = (__bf16)aA[mt][nt][r];
          z2b[(size_t)n * 256 + c] = (__bf16)aB[mt][nt][r];
        }
      }
  }
}

// ---------------- fused message kernel v8: seg-sum via MFMA, no s_hT/scan ----------------
// C-layout (edges-in-regs) is repacked to B-frag (edges-in-k) with ds_bpermute,
// then agg[seg][col] = Indicator(seg,e) @ hid(col,e) on the MFMA pipe; results
// scattered with masked atomics. LDS drops 37.9KB -> ~4KB, one barrier only.
__global__ __launch_bounds__(256, 5) void msg_mfma_kernel(
    const __bf16* __restrict__ z1b, const __bf16* __restrict__ z2b,
    const __bf16* __restrict__ efb,
    const int* __restrict__ esrc, const int* __restrict__ edst,
    const __bf16* __restrict__ B2c, float* __restrict__ aggH)
{
  __shared__ __align__(16) __bf16 s_ef[TE][24];   // 3072 B
  __shared__ int s_src[TE];
  __shared__ int s_dst[TE];
  __shared__ int s_dseg[TE];
  __shared__ unsigned char s_seg[TE];
  __shared__ int s_nseg;

  int tid = threadIdx.x, e0 = blockIdx.x * TE;

  if (tid < TE) {
    int d = edst[e0 + tid];
    s_dst[tid] = d;
    int dp = (tid == 0) ? (d ^ 1) : edst[e0 + tid - 1];
    unsigned long long mb = __ballot(d != dp);
    unsigned long long below = mb & (~0ull >> (63 - tid));
    int seg = (int)__popcll(below) - 1;   // bit0 always set -> seg(0)=0
    s_seg[tid] = (unsigned char)seg;
    if (d != dp) s_dseg[seg] = d;
    if (tid == 0) s_nseg = (int)__popcll(mb);
  } else if (tid < 2 * TE) {
    s_src[tid - TE] = esrc[e0 + tid - TE];
  }
  {
    int e = tid >> 2, t4 = tid & 3;
    if (t4 < 2)
      *(bf16x8*)&s_ef[e][t4 * 8] =
          *(const bf16x8*)(efb + (size_t)(e0 + e) * 16 + t4 * 8);
  }
  __syncthreads();

  const int wv = tid >> 6, ln = tid & 63, lc = ln & 15, qd = ln >> 4;

  const int nseg = __builtin_amdgcn_readfirstlane(s_nseg);
  const int nst = (nseg + 15) >> 4;

  // identity B fragment: C[e][c] = A[e][c] + A[e][c+16] (z1[src]+z2[dst])
  bf16x8 bI;
  #pragma unroll
  for (int j = 0; j < 8; j++)
    bI[j] = (__bf16)((lc == (qd & 1) * 8 + j) ? 1.0f : 0.0f);

  // z row pointers: qd<2 supplies z1[src] k-halves, qd>=2 z2[dst]
  const __bf16* pz[4];
  #pragma unroll
  for (int mt = 0; mt < 4; mt++) {
    int m = mt * 16 + lc;
    int row = (qd < 2) ? s_src[m] : s_dst[m];
    pz[mt] = ((qd < 2) ? z1b : z2b) + (size_t)row * 256 + (qd & 1) * 8;
  }

  // ef A-fragments (rows = edges), reused across all 4 col groups
  bf16x8 aef[4];
  #pragma unroll
  for (int mt = 0; mt < 4; mt++)
    aef[mt] = *(const bf16x8*)&s_ef[mt * 16 + lc][(qd & 1) * 8];

  // segment-id bytes for this lane's indicator k-slices: e = kf*32 + qd*8 + j
  unsigned int segk[2][2];
  #pragma unroll
  for (int kf = 0; kf < 2; kf++) {
    const unsigned int* sp = (const unsigned int*)&s_seg[kf * 32 + qd * 8];
    segk[kf][0] = sp[0];
    segk[kf][1] = sp[1];
  }
  // indicator A-frags for segment tile 0: A[seg=lc][e] = (seg_of(e)==lc)
  bf16x8 ind0[2];
  #pragma unroll
  for (int kf = 0; kf < 2; kf++)
    #pragma unroll
    for (int j = 0; j < 8; j++) {
      int b = (segk[kf][j >> 2] >> (8 * (j & 3))) & 255;
      ind0[kf][j] = (b == lc) ? (__bf16)1.0f : (__bf16)0.0f;
    }

  // dst rows for tile-0 segments this lane will scatter (garbage if masked)
  int rb0[4];
  #pragma unroll
  for (int r = 0; r < 4; r++)
    rb0[r] = s_dseg[qd * 4 + r];

  // bpermute source-lane byte addresses:
  //  w<2: src lane = lc + 16*((2qd)&3);  w>=2: src lane = lc + 16*((2qd+1)&3)
  const int aw0 = 4 * lc + (qd & 1) * 128;
  const int aw1 = aw0 + 64;

  #pragma unroll
  for (int hf = 0; hf < 2; hf++) {
    #pragma unroll
    for (int nt = 0; nt < 2; nt++) {
      const int cb = hf * 128 + wv * 32 + nt * 16;
      bf16x8 bw = *(const bf16x8*)(B2c + (size_t)(cb + lc) * 32 + qd * 8);
      int pr[4][2];
      #pragma unroll
      for (int mt = 0; mt < 4; mt++) {
        bf16x8 az = *(const bf16x8*)(pz[mt] + cb);
        f32x4 z; z[0] = 0.f; z[1] = 0.f; z[2] = 0.f; z[3] = 0.f;
        f32x4 acc = __builtin_amdgcn_mfma_f32_16x16x32_bf16(az, bI, z, 0, 0, 0);
        acc = __builtin_amdgcn_mfma_f32_16x16x32_bf16(aef[mt], bw, acc, 0, 0, 0);
        bf16x2 p0, p1;
        p0[0] = (__bf16)silu_f(acc[0]); p0[1] = (__bf16)silu_f(acc[1]);
        p1[0] = (__bf16)silu_f(acc[2]); p1[1] = (__bf16)silu_f(acc[3]);
        pr[mt][0] = __builtin_bit_cast(int, p0);
        pr[mt][1] = __builtin_bit_cast(int, p1);
      }
      // cross-lane repack: edges-in-regs -> edges-in-k B-fragments
      union { bf16x8 v; int d[4]; } fr[2];
      #pragma unroll
      for (int kf = 0; kf < 2; kf++)
        #pragma unroll
        for (int w = 0; w < 4; w++) {
          int addr = (w < 2) ? aw0 : aw1;
          int lo = __builtin_amdgcn_ds_bpermute(addr, pr[kf * 2 + 0][w & 1]);
          int hi = __builtin_amdgcn_ds_bpermute(addr, pr[kf * 2 + 1][w & 1]);
          fr[kf].d[w] = (qd < 2) ? lo : hi;
        }
      // segment reduction on the MFMA pipe + atomic scatter
      for (int st = 0; st < nst; st++) {
        bf16x8 i0, i1;
        if (st == 0) {
          i0 = ind0[0]; i1 = ind0[1];
        } else {
          int tgt = st * 16 + lc;
          #pragma unroll
          for (int j = 0; j < 8; j++) {
            int b0 = (segk[0][j >> 2] >> (8 * (j & 3))) & 255;
            int b1 = (segk[1][j >> 2] >> (8 * (j & 3))) & 255;
            i0[j] = (b0 == tgt) ? (__bf16)1.0f : (__bf16)0.0f;
            i1[j] = (b1 == tgt) ? (__bf16)1.0f : (__bf16)0.0f;
          }
        }
        f32x4 s; s[0] = 0.f; s[1] = 0.f; s[2] = 0.f; s[3] = 0.f;
        s = __builtin_amdgcn_mfma_f32_16x16x32_bf16(i0, fr[0].v, s, 0, 0, 0);
        s = __builtin_amdgcn_mfma_f32_16x16x32_bf16(i1, fr[1].v, s, 0, 0, 0);
        #pragma unroll
        for (int r = 0; r < 4; r++) {
          int seg = st * 16 + qd * 4 + r;
          if (seg < nseg) {
            int row = (st == 0) ? rb0[r] : s_dseg[seg];
            atomicAdd(&aggH[(size_t)row * 256 + cb + lc], s[r]);
          }
        }
      }
    }
  }
}

// ---------------- fused node update MLP v4: 512 threads, 64 nodes + next-layer zprep ----------------
__global__ __launch_bounds__(512, 2) void upd_mfma_kernel(
    float* __restrict__ h, __bf16* __restrict__ hb,
    float* __restrict__ aggH, const float* __restrict__ degf,
    const __bf16* __restrict__ uW1ft, const float* __restrict__ b1,
    const float* __restrict__ b2u,
    const __bf16* __restrict__ uW2t, const float* __restrict__ b2,
    int do_z, const float* __restrict__ nb1,
    const __bf16* __restrict__ nW1at, const __bf16* __restrict__ nW1bt,
    __bf16* __restrict__ z1b, __bf16* __restrict__ z2b)
{
  __shared__ __bf16 s_u[64][392];    // [h(128) | agg(256)] + 8 pad
  __shared__ __bf16 s_uh[64][264];   // 256 hidden cols + 8 pad
  int tid = threadIdx.x, n0 = blockIdx.x * 64;
  {
    int n = tid >> 3, t8 = tid & 7;  // 8 threads per node
    const bf16x8* hr = (const bf16x8*)(hb + (size_t)(n0 + n) * 128);
    #pragma unroll
    for (int i = 0; i < 2; i++)
      *(bf16x8*)&s_u[n][t8 * 8 + 64 * i] = hr[t8 + 8 * i];
    const float* sr = aggH + (size_t)(n0 + n) * 256;
    #pragma unroll
    for (int i = 0; i < 4; i++) {
      int col = t8 * 8 + i * 64;
      float4 a = *(const float4*)(sr + col);
      float4 b = *(const float4*)(sr + col + 4);
      bf16x8 o;
      o[0] = (__bf16)a.x; o[1] = (__bf16)a.y; o[2] = (__bf16)a.z; o[3] = (__bf16)a.w;
      o[4] = (__bf16)b.x; o[5] = (__bf16)b.y; o[6] = (__bf16)b.z; o[7] = (__bf16)b.w;
      *(bf16x8*)&s_u[n][128 + col] = o;
    }
  }
  __syncthreads();
  const int wv = tid >> 6, ln = tid & 63, lc = ln & 15, qd = ln >> 4;  // wv 0..7

  float dg[4][4];
  #pragma unroll
  for (int mt = 0; mt < 4; mt++)
    #pragma unroll
    for (int r = 0; r < 4; r++)
      dg[mt][r] = degf[n0 + mt * 16 + qd * 4 + r];

  // ---- GEMM1: K=384, wave owns cols wv*32 + nt*16 + lc ----
  {
    f32x4 acc1[4][2];
    #pragma unroll
    for (int nt = 0; nt < 2; nt++) {
      int c = wv * 32 + nt * 16 + lc;
      float bv = b1[c];
      float b2uv = b2u[c];
      #pragma unroll
      for (int mt = 0; mt < 4; mt++)
        #pragma unroll
        for (int r = 0; r < 4; r++)
          acc1[mt][nt][r] = bv + dg[mt][r] * b2uv;
    }
    #pragma unroll
    for (int kt = 0; kt < 12; kt++) {
      bf16x8 af[4];
      #pragma unroll
      for (int mt = 0; mt < 4; mt++)
        af[mt] = *(const bf16x8*)&s_u[mt * 16 + lc][kt * 32 + qd * 8];
      bf16x8 bw[2];
      #pragma unroll
      for (int nt = 0; nt < 2; nt++)
        bw[nt] = *(const bf16x8*)(uW1ft +
                 (size_t)(wv * 32 + nt * 16 + lc) * 384 + kt * 32 + qd * 8);
      #pragma unroll
      for (int mt = 0; mt < 4; mt++)
        #pragma unroll
        for (int nt = 0; nt < 2; nt++)
          acc1[mt][nt] = __builtin_amdgcn_mfma_f32_16x16x32_bf16(af[mt], bw[nt], acc1[mt][nt], 0, 0, 0);
    }
    #pragma unroll
    for (int mt = 0; mt < 4; mt++)
      #pragma unroll
      for (int nt = 0; nt < 2; nt++) {
        int cc = wv * 32 + nt * 16 + lc;
        #pragma unroll
        for (int r = 0; r < 4; r++)
          s_uh[mt * 16 + qd * 4 + r][cc] = (__bf16)silu_f(acc1[mt][nt][r]);
      }
  }
  __syncthreads();

  // ---- GEMM2: K=256, wave owns output cols ow = wv*16 + lc ----
  const int ow = wv * 16 + lc;
  f32x4 acc2[4];
  {
    float bv = b2[ow];
    #pragma unroll
    for (int mt = 0; mt < 4; mt++) {
      acc2[mt][0] = bv; acc2[mt][1] = bv; acc2[mt][2] = bv; acc2[mt][3] = bv;
    }
  }
  #pragma unroll
  for (int kt = 0; kt < 8; kt++) {
    bf16x8 a2[4];
    #pragma unroll
    for (int mt = 0; mt < 4; mt++)
      a2[mt] = *(const bf16x8*)&s_uh[mt * 16 + lc][kt * 32 + qd * 8];
    bf16x8 b2w = *(const bf16x8*)(uW2t + (size_t)ow * 256 + kt * 32 + qd * 8);
    #pragma unroll
    for (int mt = 0; mt < 4; mt++)
      acc2[mt] = __builtin_amdgcn_mfma_f32_16x16x32_bf16(a2[mt], b2w, acc2[mt], 0, 0, 0);
  }

  // residual epilogue
  #pragma unroll
  for (int mt = 0; mt < 4; mt++)
    #pragma unroll
    for (int r = 0; r < 4; r++) {
      int n = n0 + mt * 16 + qd * 4 + r;
      float v = h[(size_t)n * 128 + ow] + acc2[mt][r];
      h[(size_t)n * 128 + ow] = v;
      hb[(size_t)n * 128 + ow] = (__bf16)v;
    }

  // ---- fused zprep for next layer ----
  if (do_z) {
    __syncthreads();
    {
      float4 zz = make_float4(0.f, 0.f, 0.f, 0.f);
      float4* ap = (float4*)(aggH + (size_t)n0 * 256);
      for (int i = tid; i < 64 * 256 / 4; i += 512) ap[i] = zz;
      int n = tid >> 3, t8 = tid & 7;
      const bf16x8* hr = (const bf16x8*)(hb + (size_t)(n0 + n) * 128);
      #pragma unroll
      for (int i = 0; i < 2; i++)
        *(bf16x8*)&s_u[n][t8 * 8 + 64 * i] = hr[t8 + 8 * i];
    }
    __syncthreads();
    f32x4 aA[4][2], aB[4][2];
    #pragma unroll
    for (int nt = 0; nt < 2; nt++) {
      float bv = nb1[wv * 32 + nt * 16 + lc];
      #pragma unroll
      for (int mt = 0; mt < 4; mt++) {
        aA[mt][nt][0] = 0.f; aA[mt][nt][1] = 0.f;
        aA[mt][nt][2] = 0.f; aA[mt][nt][3] = 0.f;
        aB[mt][nt][0] = bv; aB[mt][nt][1] = bv;
        aB[mt][nt][2] = bv; aB[mt][nt][3] = bv;
      }
    }
    #pragma unroll
    for (int kt = 0; kt < 4; kt++) {
      bf16x8 af[4];
      #pragma unroll
      for (int mt = 0; mt < 4; mt++)
        af[mt] = *(const bf16x8*)&s_u[mt * 16 + lc][kt * 32 + qd * 8];
      bf16x8 bwA[2], bwB[2];
      #pragma unroll
      for (int nt = 0; nt < 2; nt++) {
        int c = wv * 32 + nt * 16 + lc;
        bwA[nt] = *(const bf16x8*)(nW1at + (size_t)c * 128 + kt * 32 + qd * 8);
        bwB[nt] = *(const bf16x8*)(nW1bt + (size_t)c * 128 + kt * 32 + qd * 8);
      }
      #pragma unroll
      for (int mt = 0; mt < 4; mt++)
        #pragma unroll
        for (int nt = 0; nt < 2; nt++) {
          aA[mt][nt] = __builtin_amdgcn_mfma_f32_16x16x32_bf16(af[mt], bwA[nt], aA[mt][nt], 0, 0, 0);
          aB[mt][nt] = __builtin_amdgcn_mfma_f32_16x16x32_bf16(af[mt], bwB[nt], aB[mt][nt], 0, 0, 0);
        }
    }
    #pragma unroll
    for (int mt = 0; mt < 4; mt++)
      #pragma unroll
      for (int nt = 0; nt < 2; nt++) {
        int c = wv * 32 + nt * 16 + lc;
        #pragma unroll
        for (int r = 0; r < 4; r++) {
          int n = n0 + mt * 16 + qd * 4 + r;
          z1b[(size_t)n * 256 + c] = (__bf16)aA[mt][nt][r];
          z2b[(size_t)n * 256 + c] = (__bf16)aB[mt][nt][r];
        }
      }
  }
}

// ---------------- readout ----------------
__global__ __launch_bounds__(128) void readout_sum_kernel(
    const float* __restrict__ h, const int* __restrict__ batch,
    float* __restrict__ gsum, float* __restrict__ gcnt)
{
  int j = threadIdx.x;
  int n0 = blockIdx.x * 128;
  float acc = 0.f, cacc = 0.f;
  int cur = batch[n0];
  for (int i = 0; i < 128; i++) {
    int b = batch[n0 + i];
    if (b != cur) {
      atomicAdd(&gsum[cur * 128 + j], acc);
      if (j == 0) atomicAdd(&gcnt[cur], cacc);
      acc = 0.f; cacc = 0.f; cur = b;
    }
    acc += h[(size_t)(n0 + i) * 128 + j];
    cacc += 1.f;
  }
  atomicAdd(&gsum[cur * 128 + j], acc);
  if (j == 0) atomicAdd(&gcnt[cur], cacc);
}

__global__ __launch_bounds__(256) void readout_mlp_kernel(
    const float* __restrict__ gsum, const float* __restrict__ gcnt,
    const float* __restrict__ W1, const float* __restrict__ b1,
    const float* __restrict__ W2, const float* __restrict__ b2,
    float* __restrict__ out)
{
  __shared__ float g[8][128];
  __shared__ float hid[8][256];
  int tid = threadIdx.x;
  for (int i = tid; i < 8 * 128; i += 256) {
    int b = i >> 7, c = i & 127;
    g[b][c] = gsum[i] / fmaxf(gcnt[b], 1.0f);
  }
  __syncthreads();
  {
    float bb = b1[tid];
    float a[8];
    #pragma unroll
    for (int b = 0; b < 8; b++) a[b] = bb;
    for (int k = 0; k < 128; k++) {
      float w = W1[k * 256 + tid];
      #pragma unroll
      for (int b = 0; b < 8; b++) a[b] += g[b][k] * w;
    }
    #pragma unroll
    for (int b = 0; b < 8; b++) hid[b][tid] = silu_f(a[b]);
  }
  __syncthreads();
  int j = tid & 63, bg = tid >> 6;
  float a0 = b2[j], a1 = b2[j];
  for (int k = 0; k < 256; k++) {
    float w = W2[k * 64 + j];
    a0 += hid[bg * 2 + 0][k] * w;
    a1 += hid[bg * 2 + 1][k] * w;
  }
  out[(bg * 2 + 0) * 64 + j] = a0;
  out[(bg * 2 + 1) * 64 + j] = a1;
}

extern "C" void kernel_launch(void* const* d_in, const int* in_sizes, int n_in,
                              void* d_out, int out_size, void* d_ws, size_t ws_size,
                              hipStream_t stream) {
  const float* pos   = (const float*)d_in[0];
  const float* xfeat = (const float*)d_in[1];
  const int*   eidx  = (const int*)d_in[2];
  const int*   batch = (const int*)d_in[3];
  const float* eW1 = (const float*)d_in[4];
  const float* eb1 = (const float*)d_in[5];
  const float* eW2 = (const float*)d_in[6];
  const float* eb2 = (const float*)d_in[7];
  const float* mW1 = (const float*)d_in[8];
  const float* mb1 = (const float*)d_in[9];
  const float* mW2 = (const float*)d_in[10];
  const float* mb2 = (const float*)d_in[11];
  const float* uW1 = (const float*)d_in[12];
  const float* ub1 = (const float*)d_in[13];
  const float* uW2 = (const float*)d_in[14];
  const float* ub2 = (const float*)d_in[15];
  const float* rW1 = (const float*)d_in[16];
  const float* rb1 = (const float*)d_in[17];
  const float* rW2 = (const float*)d_in[18];
  const float* rb2 = (const float*)d_in[19];

  const int* srcI = eidx;
  const int* dstI = eidx + NEDGES;

  char* base = (char*)d_ws;
  float* h    = (float*)base;  base += (size_t)NATOMS * 128 * 4;
  float* aggH = (float*)base;  base += (size_t)NATOMS * 256 * 4;
  __bf16* z1b = (__bf16*)base; base += (size_t)NATOMS * 256 * 2;
  __bf16* z2b = (__bf16*)base; base += (size_t)NATOMS * 256 * 2;
  __bf16* hb  = (__bf16*)base; base += (size_t)NATOMS * 128 * 2;
  __bf16* efb = (__bf16*)base; base += (size_t)NEDGES * 16 * 2;
  __bf16* W1at = (__bf16*)base; base += (size_t)NLAYERS * 256 * 128 * 2;
  __bf16* W1bt = (__bf16*)base; base += (size_t)NLAYERS * 256 * 128 * 2;
  __bf16* B2c  = (__bf16*)base; base += (size_t)NLAYERS * 256 * 32 * 2;
  __bf16* uW1ft = (__bf16*)base; base += (size_t)NLAYERS * 256 * 384 * 2;
  __bf16* uW2t = (__bf16*)base; base += (size_t)NLAYERS * 128 * 256 * 2;
  float* b2u  = (float*)base;  base += (size_t)NLAYERS * 256 * 4;
  float* degf = (float*)base;  base += (size_t)NATOMS * 4;
  float* gsum = (float*)base;  base += 8 * 128 * 4;
  float* gcnt = (float*)base;  base += 8 * 4;
  int* counts = (int*)base;    base += (size_t)NATOMS * 4;
  int* cursor = (int*)base;    base += (size_t)NATOMS * 4;
  int* esrc   = (int*)base;    base += (size_t)NEDGES * 4;
  int* edst   = (int*)base;    base += (size_t)NEDGES * 4;

  // counts must be zeroed before front_kernel's hist section
  hipMemsetAsync(counts, 0, NATOMS * sizeof(int), stream);

  // merged front: weight prep + dst histogram + embedding
  front_kernel<<<NB_PREP + NB_HIST + NB_EMB, 256, 0, stream>>>(
      mW1, mW2, uW1, uW2, mb2, W1at, W1bt, B2c, uW1ft, uW2t, b2u,
      dstI, counts, xfeat, eW1, eb1, eW2, eb2, h, hb);

  scan_kernel<<<1, 1024, 0, stream>>>(counts, cursor, degf);
  scatter_rbf_kernel<<<NEDGES / 256, 256, 0, stream>>>(
      srcI, dstI, cursor, pos, esrc, edst, efb);

  // zprep for layer 0 (also zeros aggH)
  zprep_kernel<<<NATOMS / 64, 256, 0, stream>>>(
      hb, mb1, W1at, W1bt, z1b, z2b, aggH);

  for (int l = 0; l < NLAYERS; l++) {
    int ln = (l < NLAYERS - 1) ? (l + 1) : l;
    msg_mfma_kernel<<<NEDGES / TE, 256, 0, stream>>>(
        z1b, z2b, efb, esrc, edst,
        B2c + (size_t)l * 256 * 32, aggH);
    upd_mfma_kernel<<<NATOMS / 64, 512, 0, stream>>>(
        h, hb, aggH, degf,
        uW1ft + (size_t)l * 256 * 384, ub1 + (size_t)l * 256,
        b2u + (size_t)l * 256,
        uW2t + (size_t)l * 128 * 256, ub2 + (size_t)l * 128,
        (l < NLAYERS - 1) ? 1 : 0,
        mb1 + (size_t)ln * 256,
        W1at + (size_t)ln * 256 * 128, W1bt + (size_t)ln * 256 * 128,
        z1b, z2b);
  }

  hipMemsetAsync(gsum, 0, (8 * 128 + 8) * sizeof(float), stream);
  readout_sum_kernel<<<NATOMS / 128, 128, 0, stream>>>(h, batch, gsum, gcnt);
  readout_mlp_kernel<<<1, 256, 0, stream>>>(gsum, gcnt, rW1, rb1, rW2, rb2,
                                            (float*)d_out);
}

// Round 2
// 599.209 us; speedup vs baseline: 1.1833x; 1.1833x over previous
//
#include <hip/hip_runtime.h>
#include <math.h>

#define NATOMS 16384
#define NEDGES 524288
#define NLAYERS 4
#define TE 64      // edges per block in msg kernel

typedef __bf16 bf16x8 __attribute__((ext_vector_type(8)));
typedef __bf16 bf16x4 __attribute__((ext_vector_type(4)));
typedef __bf16 bf16x2 __attribute__((ext_vector_type(2)));
typedef float f32x4 __attribute__((ext_vector_type(4)));

// fast silu: x * rcp(1+exp(-x))
__device__ __forceinline__ float silu_f(float x) {
  return x * __builtin_amdgcn_rcpf(1.0f + __expf(-x));
}

// ---------------- CSR preprocessing ----------------
__global__ __launch_bounds__(1024) void scan_kernel(
    const int* __restrict__ counts, int* __restrict__ cursor,
    float* __restrict__ degf)
{
  __shared__ int s_tot[1024];
  int tid = threadIdx.x;
  int v[16];
  {
    const int4* cp = (const int4*)(counts + tid * 16);
    int4 a = cp[0], b = cp[1], c = cp[2], d = cp[3];
    v[0]=a.x; v[1]=a.y; v[2]=a.z; v[3]=a.w;
    v[4]=b.x; v[5]=b.y; v[6]=b.z; v[7]=b.w;
    v[8]=c.x; v[9]=c.y; v[10]=c.z; v[11]=c.w;
    v[12]=d.x; v[13]=d.y; v[14]=d.z; v[15]=d.w;
  }
  int tot = 0;
  #pragma unroll
  for (int i = 0; i < 16; i++) tot += v[i];
  s_tot[tid] = tot;
  __syncthreads();
  for (int off = 1; off < 1024; off <<= 1) {
    int t = (tid >= off) ? s_tot[tid - off] : 0;
    __syncthreads();
    s_tot[tid] += t;
    __syncthreads();
  }
  int run = s_tot[tid] - tot;   // exclusive prefix
  #pragma unroll
  for (int i = 0; i < 16; i++) {
    cursor[tid * 16 + i] = run;
    degf[tid * 16 + i] = (float)v[i];
    run += v[i];
  }
}

// scatter + RBF fused: each edge computes its sorted slot p, writes esrc/edst
// AND its RBF features directly to efb[p].
__global__ __launch_bounds__(256) void scatter_rbf_kernel(
    const int* __restrict__ src, const int* __restrict__ dst,
    int* __restrict__ cursor, const float* __restrict__ pos,
    int* __restrict__ esrc, int* __restrict__ edst,
    __bf16* __restrict__ efb)
{
  int e = blockIdx.x * 256 + threadIdx.x;
  int s = src[e], d = dst[e];
  int p = atomicAdd(&cursor[d], 1);
  esrc[p] = s;
  edst[p] = d;
  float dx = pos[d * 3 + 0] - pos[s * 3 + 0];
  float dy = pos[d * 3 + 1] - pos[s * 3 + 1];
  float dz = pos[d * 3 + 2] - pos[s * 3 + 2];
  float dist = sqrtf(dx * dx + dy * dy + dz * dz + 1e-12f);
  float env = (dist < 10.0f)
                  ? 0.5f * (cosf(3.14159265358979f * dist * 0.1f) + 1.0f)
                  : 0.0f;
  bf16x8 o0, o1;
  #pragma unroll
  for (int i = 0; i < 16; i++) {
    float c = (10.0f / 15.0f) * (float)i;
    float t = dist - c;
    float v = env * __expf(-t * t * 1.28f);
    if (i < 8) o0[i] = (__bf16)v; else o1[i - 8] = (__bf16)v;
  }
  *(bf16x8*)(efb + (size_t)p * 16 + 0) = o0;
  *(bf16x8*)(efb + (size_t)p * 16 + 8) = o1;
}

// ---------------- merged front kernel: weight prep + dst histogram + embed ----------------
#define NB_PREP (801 * NLAYERS)
#define NB_HIST (NEDGES / 256)
#define NB_EMB  (NATOMS / 2)

__global__ __launch_bounds__(256) void front_kernel(
    const float* __restrict__ mW1, const float* __restrict__ mW2,
    const float* __restrict__ uW1, const float* __restrict__ uW2,
    const float* __restrict__ mb2,
    __bf16* __restrict__ W1at, __bf16* __restrict__ W1bt,
    __bf16* __restrict__ B2c, __bf16* __restrict__ uW1ft,
    __bf16* __restrict__ uW2t, float* __restrict__ b2u,
    const int* __restrict__ dstI, int* __restrict__ counts,
    const float* __restrict__ x, const float* __restrict__ eW1,
    const float* __restrict__ eb1, const float* __restrict__ eW2,
    const float* __restrict__ eb2, float* __restrict__ h,
    __bf16* __restrict__ hb)
{
  __shared__ float xs[2][26];
  __shared__ float hid[2][132];
  int bxf = blockIdx.x, tid = threadIdx.x;

  if (bxf < NB_PREP) {
    long l = bxf / 801;
    int bx = bxf - (int)l * 801;
    if (bx < 128) {
      int i = bx * 256 + tid;              // 256*128
      int n = i >> 7, k = i & 127;
      W1at[l * (256L * 128) + i] = (__bf16)mW1[l * (272L * 256) + (size_t)k * 256 + n];
    } else if (bx < 256) {
      int i = (bx - 128) * 256 + tid;
      int n = i >> 7, k = i & 127;
      W1bt[l * (256L * 128) + i] = (__bf16)mW1[l * (272L * 256) + (size_t)(128 + k) * 256 + n];
    } else if (bx < 288) {
      int i = (bx - 256) * 256 + tid;      // 256*32
      int c = i >> 5, k = i & 31;
      float v = (k < 16) ? mW1[l * (272L * 256) + (size_t)(256 + k) * 256 + c] : 0.0f;
      B2c[l * (256L * 32) + i] = (__bf16)v;
    } else if (bx < 672) {
      // block = one k (384 per layer), threads = n: coalesced reads, scalar mW2
      int k = bx - 288;                    // 0..383
      int n = tid;                         // 0..255
      float v;
      if (k < 128) {
        v = uW1[l * 65536 + (size_t)k * 256 + n];
      } else {
        int r = k - 128;
        v = 0.0f;
        for (int j = 0; j < 128; j++)
          v += mW2[(l * 256 + r) * 128 + j] * uW1[l * 65536 + (size_t)(128 + j) * 256 + n];
      }
      uW1ft[l * (256L * 384) + (size_t)n * 384 + k] = (__bf16)v;
    } else if (bx < 800) {
      int i = (bx - 672) * 256 + tid;      // 128*256
      int n = i >> 8, k = i & 255;
      uW2t[l * (128L * 256) + i] = (__bf16)uW2[l * (256L * 128) + (size_t)k * 128 + n];
    } else {
      int c = tid;
      float acc = 0.0f;
      for (int j = 0; j < 128; j++)
        acc += mb2[l * 128 + j] * uW1[l * 65536 + (size_t)(128 + j) * 256 + c];
      b2u[l * 256 + c] = acc;
    }
  } else if (bxf < NB_PREP + NB_HIST) {
    int e = (bxf - NB_PREP) * 256 + tid;
    atomicAdd(&counts[dstI[e]], 1);
  } else {
    int nb = bxf - (NB_PREP + NB_HIST);
    int hf = tid >> 7, j = tid & 127;
    int n = nb * 2 + hf;
    if (j < 26) xs[hf][j] = x[(size_t)n * 26 + j];
    __syncthreads();
    float acc = eb1[j];
    #pragma unroll
    for (int k = 0; k < 26; k++) acc += xs[hf][k] * eW1[k * 128 + j];
    hid[hf][j] = silu_f(acc);
    __syncthreads();
    float acc2 = eb2[j];
    #pragma unroll 8
    for (int k = 0; k < 128; k++) acc2 += hid[hf][k] * eW2[k * 128 + j];
    h[(size_t)n * 128 + j] = acc2;
    hb[(size_t)n * 128 + j] = (__bf16)acc2;
  }
}

// ---------------- zprep (layer 0 only): z1b, z2b; zeros aggH ----------------
__global__ __launch_bounds__(256) void zprep_kernel(
    const __bf16* __restrict__ hb, const float* __restrict__ b1,
    const __bf16* __restrict__ W1at, const __bf16* __restrict__ W1bt,
    __bf16* __restrict__ z1b, __bf16* __restrict__ z2b, float* __restrict__ aggH)
{
  __shared__ __bf16 s_n[64][136];
  int tid = threadIdx.x, n0 = blockIdx.x * 64;
  {
    int n = tid >> 2, t4 = tid & 3;
    const bf16x8* hr = (const bf16x8*)(hb + (size_t)(n0 + n) * 128);
    #pragma unroll
    for (int i = 0; i < 4; i++)
      *(bf16x8*)&s_n[n][t4 * 8 + 32 * i] = hr[t4 + 4 * i];
  }
  {
    float4 zz = make_float4(0.f, 0.f, 0.f, 0.f);
    float4* ap = (float4*)(aggH + (size_t)n0 * 256);
    for (int i = tid; i < 64 * 256 / 4; i += 256) ap[i] = zz;
  }
  __syncthreads();
  const int wv = tid >> 6, ln = tid & 63, lc = ln & 15, qd = ln >> 4;
  for (int cp = 0; cp < 2; cp++) {
    f32x4 aA[4][2], aB[4][2];
    #pragma unroll
    for (int nt = 0; nt < 2; nt++) {
      float bv = b1[cp * 128 + wv * 32 + nt * 16 + lc];
      #pragma unroll
      for (int mt = 0; mt < 4; mt++) {
        aA[mt][nt][0] = 0.f; aA[mt][nt][1] = 0.f;
        aA[mt][nt][2] = 0.f; aA[mt][nt][3] = 0.f;
        aB[mt][nt][0] = bv; aB[mt][nt][1] = bv;
        aB[mt][nt][2] = bv; aB[mt][nt][3] = bv;
      }
    }
    #pragma unroll
    for (int kt = 0; kt < 4; kt++) {
      bf16x8 af[4];
      #pragma unroll
      for (int mt = 0; mt < 4; mt++)
        af[mt] = *(const bf16x8*)&s_n[mt * 16 + lc][kt * 32 + qd * 8];
      bf16x8 bwA[2], bwB[2];
      #pragma unroll
      for (int nt = 0; nt < 2; nt++) {
        int c = cp * 128 + wv * 32 + nt * 16 + lc;
        bwA[nt] = *(const bf16x8*)(W1at + (size_t)c * 128 + kt * 32 + qd * 8);
        bwB[nt] = *(const bf16x8*)(W1bt + (size_t)c * 128 + kt * 32 + qd * 8);
      }
      #pragma unroll
      for (int mt = 0; mt < 4; mt++)
        #pragma unroll
        for (int nt = 0; nt < 2; nt++) {
          aA[mt][nt] = __builtin_amdgcn_mfma_f32_16x16x32_bf16(af[mt], bwA[nt], aA[mt][nt], 0, 0, 0);
          aB[mt][nt] = __builtin_amdgcn_mfma_f32_16x16x32_bf16(af[mt], bwB[nt], aB[mt][nt], 0, 0, 0);
        }
    }
    #pragma unroll
    for (int mt = 0; mt < 4; mt++)
      #pragma unroll
      for (int nt = 0; nt < 2; nt++) {
        int c = cp * 128 + wv * 32 + nt * 16 + lc;
        #pragma unroll
        for (int r = 0; r < 4; r++) {
          int n = n0 + mt * 16 + qd * 4 + r;
          z1b[(size_t)n * 256 + c] = (__bf16)aA[mt][nt][r];
          z2b[(size_t)n * 256 + c] = (__bf16)aB[mt][nt][r];
        }
      }
  }
}

// ---------------- fused message kernel v9: two-pass half-width s_hT ----------------
// Round-0 structure (identity-MFMA gather-add + LDS transpose + per-col scan),
// but s_hT halved to [128][70] and the scan split 2 threads/col (32 rows each;
// runs straddling row 32 issue two atomics to the same address - additive, OK).
// LDS 37.9KB -> 21.5KB => 7 blocks/CU instead of 4. Pad 70: write pattern
// (3*lc+8*mt+2*qd)%32 and read pattern (3*j)%32 are both <=2-way (free).
__global__ __launch_bounds__(256, 7) void msg_mfma_kernel(
    const __bf16* __restrict__ z1b, const __bf16* __restrict__ z2b,
    const __bf16* __restrict__ efb,
    const int* __restrict__ esrc, const int* __restrict__ edst,
    const __bf16* __restrict__ B2c, float* __restrict__ aggH)
{
  __shared__ __align__(16) __bf16 s_hT[128][70];   // 17920 B
  __shared__ __align__(16) __bf16 s_ef[TE][24];    // 3072 B
  __shared__ int s_src[TE];
  __shared__ int s_dst[TE];
  __shared__ unsigned int s_mask[2];

  int tid = threadIdx.x, e0 = blockIdx.x * TE;

  if (tid < TE) {
    int d = edst[e0 + tid];
    s_dst[tid] = d;
    int dp = (tid == 0) ? (d ^ 1) : edst[e0 + tid - 1];
    unsigned long long mb = __ballot(d != dp);
    if (tid == 0) { s_mask[0] = (unsigned int)mb; s_mask[1] = (unsigned int)(mb >> 32); }
  } else if (tid < 2 * TE) {
    s_src[tid - TE] = esrc[e0 + tid - TE];
  }
  {
    int e = tid >> 2, t4 = tid & 3;
    if (t4 < 2)
      *(bf16x8*)&s_ef[e][t4 * 8] =
          *(const bf16x8*)(efb + (size_t)(e0 + e) * 16 + t4 * 8);
  }
  __syncthreads();

  const int wv = tid >> 6, ln = tid & 63, lc = ln & 15, qd = ln >> 4;

  // identity B fragment: C[e][c] = A[e][c] + A[e][c+16] (z1[src]+z2[dst])
  bf16x8 bI;
  #pragma unroll
  for (int j = 0; j < 8; j++)
    bI[j] = (__bf16)((lc == (qd & 1) * 8 + j) ? 1.0f : 0.0f);

  // z row pointers: qd<2 supplies z1[src] k-halves, qd>=2 z2[dst]
  const __bf16* pz[4];
  #pragma unroll
  for (int mt = 0; mt < 4; mt++) {
    int m = mt * 16 + lc;
    int row = (qd < 2) ? s_src[m] : s_dst[m];
    pz[mt] = ((qd < 2) ? z1b : z2b) + (size_t)row * 256 + (qd & 1) * 8;
  }

  // ef A-fragments (rows = edges), reused across both passes
  bf16x8 aef[4];
  #pragma unroll
  for (int mt = 0; mt < 4; mt++)
    aef[mt] = *(const bf16x8*)&s_ef[mt * 16 + lc][(qd & 1) * 8];

  // scan-role constants: 2 threads per column, 32 rows each (wave-uniform half)
  const int sj = tid & 127;
  const int srow0 = (tid >> 7) * 32;
  const unsigned int smask = __builtin_amdgcn_readfirstlane(s_mask[tid >> 7]);

  #pragma unroll
  for (int hf = 0; hf < 2; hf++) {
    if (hf) __syncthreads();   // protect s_hT until previous scan done

    #pragma unroll
    for (int nt = 0; nt < 2; nt++) {
      const int cb = hf * 128 + wv * 32 + nt * 16;
      bf16x8 bw = *(const bf16x8*)(B2c + (size_t)(cb + lc) * 32 + qd * 8);
      #pragma unroll
      for (int mt = 0; mt < 4; mt++) {
        bf16x8 az = *(const bf16x8*)(pz[mt] + cb);
        f32x4 z; z[0] = 0.f; z[1] = 0.f; z[2] = 0.f; z[3] = 0.f;
        f32x4 acc = __builtin_amdgcn_mfma_f32_16x16x32_bf16(az, bI, z, 0, 0, 0);
        acc = __builtin_amdgcn_mfma_f32_16x16x32_bf16(aef[mt], bw, acc, 0, 0, 0);
        bf16x2 p0, p1;
        p0[0] = (__bf16)silu_f(acc[0]); p0[1] = (__bf16)silu_f(acc[1]);
        p1[0] = (__bf16)silu_f(acc[2]); p1[1] = (__bf16)silu_f(acc[3]);
        __bf16* wp = &s_hT[wv * 32 + nt * 16 + lc][mt * 16 + qd * 4];
        *(bf16x2*)wp = p0;
        *(bf16x2*)(wp + 2) = p1;
      }
    }
    __syncthreads();

    // scan: 256 threads x (1 column half): col sj, rows [srow0, srow0+32)
    {
      const int gcol = hf * 128 + sj;
      float acc = 0.0f;
      int cur = s_dst[srow0];
      #pragma unroll 8
      for (int i = 0; i < 32; i += 2) {
        bf16x2 p = *(const bf16x2*)&s_hT[sj][srow0 + i];
        if (i > 0 && ((smask >> i) & 1u)) {
          atomicAdd(&aggH[(size_t)cur * 256 + gcol], acc);
          acc = 0.0f; cur = s_dst[srow0 + i];
        }
        acc += (float)p[0];
        if ((smask >> (i + 1)) & 1u) {
          atomicAdd(&aggH[(size_t)cur * 256 + gcol], acc);
          acc = 0.0f; cur = s_dst[srow0 + i + 1];
        }
        acc += (float)p[1];
      }
      atomicAdd(&aggH[(size_t)cur * 256 + gcol], acc);
    }
  }
}

// ---------------- fused node update MLP v4: 512 threads, 64 nodes + next-layer zprep ----------------
__global__ __launch_bounds__(512, 2) void upd_mfma_kernel(
    float* __restrict__ h, __bf16* __restrict__ hb,
    float* __restrict__ aggH, const float* __restrict__ degf,
    const __bf16* __restrict__ uW1ft, const float* __restrict__ b1,
    const float* __restrict__ b2u,
    const __bf16* __restrict__ uW2t, const float* __restrict__ b2,
    int do_z, const float* __restrict__ nb1,
    const __bf16* __restrict__ nW1at, const __bf16* __restrict__ nW1bt,
    __bf16* __restrict__ z1b, __bf16* __restrict__ z2b)
{
  __shared__ __bf16 s_u[64][392];    // [h(128) | agg(256)] + 8 pad
  __shared__ __bf16 s_uh[64][264];   // 256 hidden cols + 8 pad
  int tid = threadIdx.x, n0 = blockIdx.x * 64;
  {
    int n = tid >> 3, t8 = tid & 7;  // 8 threads per node
    const bf16x8* hr = (const bf16x8*)(hb + (size_t)(n0 + n) * 128);
    #pragma unroll
    for (int i = 0; i < 2; i++)
      *(bf16x8*)&s_u[n][t8 * 8 + 64 * i] = hr[t8 + 8 * i];
    const float* sr = aggH + (size_t)(n0 + n) * 256;
    #pragma unroll
    for (int i = 0; i < 4; i++) {
      int col = t8 * 8 + i * 64;
      float4 a = *(const float4*)(sr + col);
      float4 b = *(const float4*)(sr + col + 4);
      bf16x8 o;
      o[0] = (__bf16)a.x; o[1] = (__bf16)a.y; o[2] = (__bf16)a.z; o[3] = (__bf16)a.w;
      o[4] = (__bf16)b.x; o[5] = (__bf16)b.y; o[6] = (__bf16)b.z; o[7] = (__bf16)b.w;
      *(bf16x8*)&s_u[n][128 + col] = o;
    }
  }
  __syncthreads();
  const int wv = tid >> 6, ln = tid & 63, lc = ln & 15, qd = ln >> 4;  // wv 0..7

  float dg[4][4];
  #pragma unroll
  for (int mt = 0; mt < 4; mt++)
    #pragma unroll
    for (int r = 0; r < 4; r++)
      dg[mt][r] = degf[n0 + mt * 16 + qd * 4 + r];

  // ---- GEMM1: K=384, wave owns cols wv*32 + nt*16 + lc ----
  {
    f32x4 acc1[4][2];
    #pragma unroll
    for (int nt = 0; nt < 2; nt++) {
      int c = wv * 32 + nt * 16 + lc;
      float bv = b1[c];
      float b2uv = b2u[c];
      #pragma unroll
      for (int mt = 0; mt < 4; mt++)
        #pragma unroll
        for (int r = 0; r < 4; r++)
          acc1[mt][nt][r] = bv + dg[mt][r] * b2uv;
    }
    #pragma unroll
    for (int kt = 0; kt < 12; kt++) {
      bf16x8 af[4];
      #pragma unroll
      for (int mt = 0; mt < 4; mt++)
        af[mt] = *(const bf16x8*)&s_u[mt * 16 + lc][kt * 32 + qd * 8];
      bf16x8 bw[2];
      #pragma unroll
      for (int nt = 0; nt < 2; nt++)
        bw[nt] = *(const bf16x8*)(uW1ft +
                 (size_t)(wv * 32 + nt * 16 + lc) * 384 + kt * 32 + qd * 8);
      #pragma unroll
      for (int mt = 0; mt < 4; mt++)
        #pragma unroll
        for (int nt = 0; nt < 2; nt++)
          acc1[mt][nt] = __builtin_amdgcn_mfma_f32_16x16x32_bf16(af[mt], bw[nt], acc1[mt][nt], 0, 0, 0);
    }
    #pragma unroll
    for (int mt = 0; mt < 4; mt++)
      #pragma unroll
      for (int nt = 0; nt < 2; nt++) {
        int cc = wv * 32 + nt * 16 + lc;
        #pragma unroll
        for (int r = 0; r < 4; r++)
          s_uh[mt * 16 + qd * 4 + r][cc] = (__bf16)silu_f(acc1[mt][nt][r]);
      }
  }
  __syncthreads();

  // ---- GEMM2: K=256, wave owns output cols ow = wv*16 + lc ----
  const int ow = wv * 16 + lc;
  f32x4 acc2[4];
  {
    float bv = b2[ow];
    #pragma unroll
    for (int mt = 0; mt < 4; mt++) {
      acc2[mt][0] = bv; acc2[mt][1] = bv; acc2[mt][2] = bv; acc2[mt][3] = bv;
    }
  }
  #pragma unroll
  for (int kt = 0; kt < 8; kt++) {
    bf16x8 a2[4];
    #pragma unroll
    for (int mt = 0; mt < 4; mt++)
      a2[mt] = *(const bf16x8*)&s_uh[mt * 16 + lc][kt * 32 + qd * 8];
    bf16x8 b2w = *(const bf16x8*)(uW2t + (size_t)ow * 256 + kt * 32 + qd * 8);
    #pragma unroll
    for (int mt = 0; mt < 4; mt++)
      acc2[mt] = __builtin_amdgcn_mfma_f32_16x16x32_bf16(a2[mt], b2w, acc2[mt], 0, 0, 0);
  }

  // residual epilogue
  #pragma unroll
  for (int mt = 0; mt < 4; mt++)
    #pragma unroll
    for (int r = 0; r < 4; r++) {
      int n = n0 + mt * 16 + qd * 4 + r;
      float v = h[(size_t)n * 128 + ow] + acc2[mt][r];
      h[(size_t)n * 128 + ow] = v;
      hb[(size_t)n * 128 + ow] = (__bf16)v;
    }

  // ---- fused zprep for next layer ----
  if (do_z) {
    __syncthreads();
    {
      float4 zz = make_float4(0.f, 0.f, 0.f, 0.f);
      float4* ap = (float4*)(aggH + (size_t)n0 * 256);
      for (int i = tid; i < 64 * 256 / 4; i += 512) ap[i] = zz;
      int n = tid >> 3, t8 = tid & 7;
      const bf16x8* hr = (const bf16x8*)(hb + (size_t)(n0 + n) * 128);
      #pragma unroll
      for (int i = 0; i < 2; i++)
        *(bf16x8*)&s_u[n][t8 * 8 + 64 * i] = hr[t8 + 8 * i];
    }
    __syncthreads();
    f32x4 aA[4][2], aB[4][2];
    #pragma unroll
    for (int nt = 0; nt < 2; nt++) {
      float bv = nb1[wv * 32 + nt * 16 + lc];
      #pragma unroll
      for (int mt = 0; mt < 4; mt++) {
        aA[mt][nt][0] = 0.f; aA[mt][nt][1] = 0.f;
        aA[mt][nt][2] = 0.f; aA[mt][nt][3] = 0.f;
        aB[mt][nt][0] = bv; aB[mt][nt][1] = bv;
        aB[mt][nt][2] = bv; aB[mt][nt][3] = bv;
      }
    }
    #pragma unroll
    for (int kt = 0; kt < 4; kt++) {
      bf16x8 af[4];
      #pragma unroll
      for (int mt = 0; mt < 4; mt++)
        af[mt] = *(const bf16x8*)&s_u[mt * 16 + lc][kt * 32 + qd * 8];
      bf16x8 bwA[2], bwB[2];
      #pragma unroll
      for (int nt = 0; nt < 2; nt++) {
        int c = wv * 32 + nt * 16 + lc;
        bwA[nt] = *(const bf16x8*)(nW1at + (size_t)c * 128 + kt * 32 + qd * 8);
        bwB[nt] = *(const bf16x8*)(nW1bt + (size_t)c * 128 + kt * 32 + qd * 8);
      }
      #pragma unroll
      for (int mt = 0; mt < 4; mt++)
        #pragma unroll
        for (int nt = 0; nt < 2; nt++) {
          aA[mt][nt] = __builtin_amdgcn_mfma_f32_16x16x32_bf16(af[mt], bwA[nt], aA[mt][nt], 0, 0, 0);
          aB[mt][nt] = __builtin_amdgcn_mfma_f32_16x16x32_bf16(af[mt], bwB[nt], aB[mt][nt], 0, 0, 0);
        }
    }
    #pragma unroll
    for (int mt = 0; mt < 4; mt++)
      #pragma unroll
      for (int nt = 0; nt < 2; nt++) {
        int c = wv * 32 + nt * 16 + lc;
        #pragma unroll
        for (int r = 0; r < 4; r++) {
          int n = n0 + mt * 16 + qd * 4 + r;
          z1b[(size_t)n * 256 + c] = (__bf16)aA[mt][nt][r];
          z2b[(size_t)n * 256 + c] = (__bf16)aB[mt][nt][r];
        }
      }
  }
}

// ---------------- readout ----------------
__global__ __launch_bounds__(128) void readout_sum_kernel(
    const float* __restrict__ h, const int* __restrict__ batch,
    float* __restrict__ gsum, float* __restrict__ gcnt)
{
  int j = threadIdx.x;
  int n0 = blockIdx.x * 128;
  float acc = 0.f, cacc = 0.f;
  int cur = batch[n0];
  for (int i = 0; i < 128; i++) {
    int b = batch[n0 + i];
    if (b != cur) {
      atomicAdd(&gsum[cur * 128 + j], acc);
      if (j == 0) atomicAdd(&gcnt[cur], cacc);
      acc = 0.f; cacc = 0.f; cur = b;
    }
    acc += h[(size_t)(n0 + i) * 128 + j];
    cacc += 1.f;
  }
  atomicAdd(&gsum[cur * 128 + j], acc);
  if (j == 0) atomicAdd(&gcnt[cur], cacc);
}

__global__ __launch_bounds__(256) void readout_mlp_kernel(
    const float* __restrict__ gsum, const float* __restrict__ gcnt,
    const float* __restrict__ W1, const float* __restrict__ b1,
    const float* __restrict__ W2, const float* __restrict__ b2,
    float* __restrict__ out)
{
  __shared__ float g[8][128];
  __shared__ float hid[8][256];
  int tid = threadIdx.x;
  for (int i = tid; i < 8 * 128; i += 256) {
    int b = i >> 7, c = i & 127;
    g[b][c] = gsum[i] / fmaxf(gcnt[b], 1.0f);
  }
  __syncthreads();
  {
    float bb = b1[tid];
    float a[8];
    #pragma unroll
    for (int b = 0; b < 8; b++) a[b] = bb;
    for (int k = 0; k < 128; k++) {
      float w = W1[k * 256 + tid];
      #pragma unroll
      for (int b = 0; b < 8; b++) a[b] += g[b][k] * w;
    }
    #pragma unroll
    for (int b = 0; b < 8; b++) hid[b][tid] = silu_f(a[b]);
  }
  __syncthreads();
  int j = tid & 63, bg = tid >> 6;
  float a0 = b2[j], a1 = b2[j];
  for (int k = 0; k < 256; k++) {
    float w = W2[k * 64 + j];
    a0 += hid[bg * 2 + 0][k] * w;
    a1 += hid[bg * 2 + 1][k] * w;
  }
  out[(bg * 2 + 0) * 64 + j] = a0;
  out[(bg * 2 + 1) * 64 + j] = a1;
}

extern "C" void kernel_launch(void* const* d_in, const int* in_sizes, int n_in,
                              void* d_out, int out_size, void* d_ws, size_t ws_size,
                              hipStream_t stream) {
  const float* pos   = (const float*)d_in[0];
  const float* xfeat = (const float*)d_in[1];
  const int*   eidx  = (const int*)d_in[2];
  const int*   batch = (const int*)d_in[3];
  const float* eW1 = (const float*)d_in[4];
  const float* eb1 = (const float*)d_in[5];
  const float* eW2 = (const float*)d_in[6];
  const float* eb2 = (const float*)d_in[7];
  const float* mW1 = (const float*)d_in[8];
  const float* mb1 = (const float*)d_in[9];
  const float* mW2 = (const float*)d_in[10];
  const float* mb2 = (const float*)d_in[11];
  const float* uW1 = (const float*)d_in[12];
  const float* ub1 = (const float*)d_in[13];
  const float* uW2 = (const float*)d_in[14];
  const float* ub2 = (const float*)d_in[15];
  const float* rW1 = (const float*)d_in[16];
  const float* rb1 = (const float*)d_in[17];
  const float* rW2 = (const float*)d_in[18];
  const float* rb2 = (const float*)d_in[19];

  const int* srcI = eidx;
  const int* dstI = eidx + NEDGES;

  char* base = (char*)d_ws;
  float* h    = (float*)base;  base += (size_t)NATOMS * 128 * 4;
  float* aggH = (float*)base;  base += (size_t)NATOMS * 256 * 4;
  __bf16* z1b = (__bf16*)base; base += (size_t)NATOMS * 256 * 2;
  __bf16* z2b = (__bf16*)base; base += (size_t)NATOMS * 256 * 2;
  __bf16* hb  = (__bf16*)base; base += (size_t)NATOMS * 128 * 2;
  __bf16* efb = (__bf16*)base; base += (size_t)NEDGES * 16 * 2;
  __bf16* W1at = (__bf16*)base; base += (size_t)NLAYERS * 256 * 128 * 2;
  __bf16* W1bt = (__bf16*)base; base += (size_t)NLAYERS * 256 * 128 * 2;
  __bf16* B2c  = (__bf16*)base; base += (size_t)NLAYERS * 256 * 32 * 2;
  __bf16* uW1ft = (__bf16*)base; base += (size_t)NLAYERS * 256 * 384 * 2;
  __bf16* uW2t = (__bf16*)base; base += (size_t)NLAYERS * 128 * 256 * 2;
  float* b2u  = (float*)base;  base += (size_t)NLAYERS * 256 * 4;
  float* degf = (float*)base;  base += (size_t)NATOMS * 4;
  float* gsum = (float*)base;  base += 8 * 128 * 4;
  float* gcnt = (float*)base;  base += 8 * 4;
  int* counts = (int*)base;    base += (size_t)NATOMS * 4;
  int* cursor = (int*)base;    base += (size_t)NATOMS * 4;
  int* esrc   = (int*)base;    base += (size_t)NEDGES * 4;
  int* edst   = (int*)base;    base += (size_t)NEDGES * 4;

  // counts must be zeroed before front_kernel's hist section
  hipMemsetAsync(counts, 0, NATOMS * sizeof(int), stream);

  // merged front: weight prep + dst histogram + embedding
  front_kernel<<<NB_PREP + NB_HIST + NB_EMB, 256, 0, stream>>>(
      mW1, mW2, uW1, uW2, mb2, W1at, W1bt, B2c, uW1ft, uW2t, b2u,
      dstI, counts, xfeat, eW1, eb1, eW2, eb2, h, hb);

  scan_kernel<<<1, 1024, 0, stream>>>(counts, cursor, degf);
  scatter_rbf_kernel<<<NEDGES / 256, 256, 0, stream>>>(
      srcI, dstI, cursor, pos, esrc, edst, efb);

  // zprep for layer 0 (also zeros aggH)
  zprep_kernel<<<NATOMS / 64, 256, 0, stream>>>(
      hb, mb1, W1at, W1bt, z1b, z2b, aggH);

  for (int l = 0; l < NLAYERS; l++) {
    int ln = (l < NLAYERS - 1) ? (l + 1) : l;
    msg_mfma_kernel<<<NEDGES / TE, 256, 0, stream>>>(
        z1b, z2b, efb, esrc, edst,
        B2c + (size_t)l * 256 * 32, aggH);
    upd_mfma_kernel<<<NATOMS / 64, 512, 0, stream>>>(
        h, hb, aggH, degf,
        uW1ft + (size_t)l * 256 * 384, ub1 + (size_t)l * 256,
        b2u + (size_t)l * 256,
        uW2t + (size_t)l * 128 * 256, ub2 + (size_t)l * 128,
        (l < NLAYERS - 1) ? 1 : 0,
        mb1 + (size_t)ln * 256,
        W1at + (size_t)ln * 256 * 128, W1bt + (size_t)ln * 256 * 128,
        z1b, z2b);
  }

  hipMemsetAsync(gsum, 0, (8 * 128 + 8) * sizeof(float), stream);
  readout_sum_kernel<<<NATOMS / 128, 128, 0, stream>>>(h, batch, gsum, gcnt);
  readout_mlp_kernel<<<1, 256, 0, stream>>>(gsum, gcnt, rW1, rb1, rW2, rb2,
                                            (float*)d_out);
}

// Round 3
// 583.290 us; speedup vs baseline: 1.2156x; 1.0273x over previous
//
#include <hip/hip_runtime.h>
#include <math.h>

#define NATOMS 16384
#define NEDGES 524288
#define NLAYERS 4
#define TE 64      // edges per block in msg kernel

typedef __bf16 bf16x8 __attribute__((ext_vector_type(8)));
typedef __bf16 bf16x4 __attribute__((ext_vector_type(4)));
typedef __bf16 bf16x2 __attribute__((ext_vector_type(2)));
typedef float f32x4 __attribute__((ext_vector_type(4)));

// fast silu: x * rcp(1+exp(-x))
__device__ __forceinline__ float silu_f(float x) {
  return x * __builtin_amdgcn_rcpf(1.0f + __expf(-x));
}

// ---------------- CSR preprocessing ----------------
__global__ __launch_bounds__(1024) void scan_kernel(
    const int* __restrict__ counts, int* __restrict__ cursor,
    float* __restrict__ degf)
{
  __shared__ int s_tot[1024];
  int tid = threadIdx.x;
  int v[16];
  {
    const int4* cp = (const int4*)(counts + tid * 16);
    int4 a = cp[0], b = cp[1], c = cp[2], d = cp[3];
    v[0]=a.x; v[1]=a.y; v[2]=a.z; v[3]=a.w;
    v[4]=b.x; v[5]=b.y; v[6]=b.z; v[7]=b.w;
    v[8]=c.x; v[9]=c.y; v[10]=c.z; v[11]=c.w;
    v[12]=d.x; v[13]=d.y; v[14]=d.z; v[15]=d.w;
  }
  int tot = 0;
  #pragma unroll
  for (int i = 0; i < 16; i++) tot += v[i];
  s_tot[tid] = tot;
  __syncthreads();
  for (int off = 1; off < 1024; off <<= 1) {
    int t = (tid >= off) ? s_tot[tid - off] : 0;
    __syncthreads();
    s_tot[tid] += t;
    __syncthreads();
  }
  int run = s_tot[tid] - tot;   // exclusive prefix
  #pragma unroll
  for (int i = 0; i < 16; i++) {
    cursor[tid * 16 + i] = run;
    degf[tid * 16 + i] = (float)v[i];
    run += v[i];
  }
}

// scatter + RBF fused: each edge computes its sorted slot p, writes esrc/edst
// AND its RBF features directly to efb[p].
__global__ __launch_bounds__(256) void scatter_rbf_kernel(
    const int* __restrict__ src, const int* __restrict__ dst,
    int* __restrict__ cursor, const float* __restrict__ pos,
    int* __restrict__ esrc, int* __restrict__ edst,
    __bf16* __restrict__ efb)
{
  int e = blockIdx.x * 256 + threadIdx.x;
  int s = src[e], d = dst[e];
  int p = atomicAdd(&cursor[d], 1);
  esrc[p] = s;
  edst[p] = d;
  float dx = pos[d * 3 + 0] - pos[s * 3 + 0];
  float dy = pos[d * 3 + 1] - pos[s * 3 + 1];
  float dz = pos[d * 3 + 2] - pos[s * 3 + 2];
  float dist = sqrtf(dx * dx + dy * dy + dz * dz + 1e-12f);
  float env = (dist < 10.0f)
                  ? 0.5f * (cosf(3.14159265358979f * dist * 0.1f) + 1.0f)
                  : 0.0f;
  bf16x8 o0, o1;
  #pragma unroll
  for (int i = 0; i < 16; i++) {
    float c = (10.0f / 15.0f) * (float)i;
    float t = dist - c;
    float v = env * __expf(-t * t * 1.28f);
    if (i < 8) o0[i] = (__bf16)v; else o1[i - 8] = (__bf16)v;
  }
  *(bf16x8*)(efb + (size_t)p * 16 + 0) = o0;
  *(bf16x8*)(efb + (size_t)p * 16 + 8) = o1;
}

// ---------------- merged front kernel v2 ----------------
// prep rewritten: LDS-tiled 64x64 transposes (coalesced both sides),
// 16-row-slab fusion GEMM (16-way ILP), 32-node embed blocks.
#define NB_PL   50
#define NB_PREP (NB_PL * NLAYERS)
#define NB_HIST (NEDGES / 256)
#define NB_EMB  (NATOMS / 32)

__global__ __launch_bounds__(256) void front_kernel(
    const float* __restrict__ mW1, const float* __restrict__ mW2,
    const float* __restrict__ uW1, const float* __restrict__ uW2,
    const float* __restrict__ mb2,
    __bf16* __restrict__ W1at, __bf16* __restrict__ W1bt,
    __bf16* __restrict__ B2c, __bf16* __restrict__ uW1ft,
    __bf16* __restrict__ uW2t, float* __restrict__ b2u,
    const int* __restrict__ dstI, int* __restrict__ counts,
    const float* __restrict__ x, const float* __restrict__ eW1,
    const float* __restrict__ eb1, const float* __restrict__ eW2,
    const float* __restrict__ eb2, float* __restrict__ h,
    __bf16* __restrict__ hb)
{
  __shared__ __align__(16) char smem[19712];
  int bxf = blockIdx.x, tid = threadIdx.x;

  if (bxf < NB_PREP) {
    int l = bxf / NB_PL;
    int bx = bxf - l * NB_PL;
    if (bx < 16) {
      // W1at / W1bt: transpose 64x64 tiles of mW1 rows [0,256)
      float (*tile)[65] = (float(*)[65])smem;
      int tt = bx & 7;
      int row0 = ((tt >> 2) * 64) + ((bx < 8) ? 0 : 128);   // source k-row
      int col0 = (tt & 3) * 64;                             // source col (c)
      const float* Sp = mW1 + (size_t)l * (272 * 256) + (size_t)row0 * 256 + col0;
      __bf16* Dq = ((bx < 8) ? W1at : W1bt) + (size_t)l * (256 * 128);
      int dro = (bx < 8) ? row0 : row0 - 128;
      int c = tid & 63, r4 = tid >> 6;
      #pragma unroll
      for (int i = 0; i < 16; i++)
        tile[r4 + i * 4][c] = Sp[(size_t)(r4 + i * 4) * 256 + c];
      __syncthreads();
      #pragma unroll
      for (int i = 0; i < 16; i++) {
        int dr = r4 + i * 4;
        Dq[(size_t)(col0 + dr) * 128 + dro + c] = (__bf16)tile[c][dr];
      }
    } else if (bx == 16) {
      // B2c: rows 256..271 of mW1 -> [c][k] with zero pad to k=32
      float (*t3)[257] = (float(*)[257])smem;
      const float* Sp = mW1 + (size_t)l * (272 * 256) + 256 * 256;
      #pragma unroll
      for (int i = 0; i < 16; i++) t3[i][tid] = Sp[i * 256 + tid];
      __syncthreads();
      __bf16* Dp = B2c + (size_t)l * (256 * 32) + (size_t)tid * 32;
      #pragma unroll
      for (int g = 0; g < 4; g++) {
        bf16x8 o;
        #pragma unroll
        for (int j2 = 0; j2 < 8; j2++) {
          int k = g * 8 + j2;
          o[j2] = (__bf16)((k < 16) ? t3[k][tid] : 0.0f);
        }
        *(bf16x8*)(Dp + g * 8) = o;
      }
    } else if (bx < 25) {
      // uW1ft copy part (k<128): transpose 64x64 tiles of uW1
      float (*tile)[65] = (float(*)[65])smem;
      int tt = bx - 17;
      int row0 = (tt >> 2) * 64;         // k
      int col0 = (tt & 3) * 64;          // n
      const float* Sp = uW1 + (size_t)l * 65536 + (size_t)row0 * 256 + col0;
      __bf16* Dq = uW1ft + (size_t)l * (256 * 384);
      int c = tid & 63, r4 = tid >> 6;
      #pragma unroll
      for (int i = 0; i < 16; i++)
        tile[r4 + i * 4][c] = Sp[(size_t)(r4 + i * 4) * 256 + c];
      __syncthreads();
      #pragma unroll
      for (int i = 0; i < 16; i++) {
        int dr = r4 + i * 4;
        Dq[(size_t)(col0 + dr) * 384 + row0 + c] = (__bf16)tile[c][dr];
      }
    } else if (bx < 41) {
      // fusion slab: F[r0+r][n] = sum_j mW2[r0+r][j] * uW1[128+j][n]
      float (*sA)[128] = (float(*)[128])smem;
      int r0 = (bx - 25) * 16;
      const float* Ap = mW2 + (size_t)(l * 256 + r0) * 128;
      #pragma unroll
      for (int i = 0; i < 8; i++) {
        int idx = i * 256 + tid;
        ((float*)smem)[idx] = Ap[idx];
      }
      __syncthreads();
      const float* Bp = uW1 + (size_t)l * 65536 + 128 * 256 + tid;
      float acc[16];
      #pragma unroll
      for (int r = 0; r < 16; r++) acc[r] = 0.0f;
      for (int k = 0; k < 128; k++) {
        float b = Bp[(size_t)k * 256];
        #pragma unroll
        for (int r = 0; r < 16; r++) acc[r] += sA[r][k] * b;
      }
      __bf16* Dp = uW1ft + (size_t)l * (256 * 384) + (size_t)tid * 384 + 128 + r0;
      bf16x8 o0, o1;
      #pragma unroll
      for (int r = 0; r < 8; r++) { o0[r] = (__bf16)acc[r]; o1[r] = (__bf16)acc[8 + r]; }
      *(bf16x8*)Dp = o0;
      *(bf16x8*)(Dp + 8) = o1;
    } else if (bx < 49) {
      // uW2t: transpose 64x64 tiles of uW2 (256x128)
      float (*tile)[65] = (float(*)[65])smem;
      int tt = bx - 41;
      int row0 = (tt >> 1) * 64;     // k in [0,256)
      int col0 = (tt & 1) * 64;      // n in [0,128)
      const float* Sp = uW2 + (size_t)l * (256 * 128) + (size_t)row0 * 128 + col0;
      __bf16* Dq = uW2t + (size_t)l * (128 * 256);
      int c = tid & 63, r4 = tid >> 6;
      #pragma unroll
      for (int i = 0; i < 16; i++)
        tile[r4 + i * 4][c] = Sp[(size_t)(r4 + i * 4) * 128 + c];
      __syncthreads();
      #pragma unroll
      for (int i = 0; i < 16; i++) {
        int dr = r4 + i * 4;
        Dq[(size_t)(col0 + dr) * 256 + row0 + c] = (__bf16)tile[c][dr];
      }
    } else {
      // b2u[c] = sum_j mb2[j] * uW1[128+j][c]
      int cc = tid;
      float acc = 0.0f;
      for (int j2 = 0; j2 < 128; j2++)
        acc += mb2[l * 128 + j2] * uW1[(size_t)l * 65536 + (size_t)(128 + j2) * 256 + cc];
      b2u[l * 256 + cc] = acc;
    }
  } else if (bxf < NB_PREP + NB_HIST) {
    int e = (bxf - NB_PREP) * 256 + tid;
    atomicAdd(&counts[dstI[e]], 1);
  } else {
    // embedding: 32 nodes per block, 16 accumulators per thread
    int nb = bxf - (NB_PREP + NB_HIST);
    int n0e = nb * 32;
    float* xsf = (float*)smem;                               // [32][26]
    float (*hid2)[128] = (float(*)[128])(smem + 32 * 26 * 4);
    for (int i = tid; i < 32 * 26; i += 256)
      xsf[i] = x[(size_t)n0e * 26 + i];
    __syncthreads();
    int j = tid & 127, ns = tid >> 7;
    float a1[16];
    {
      float bb = eb1[j];
      #pragma unroll
      for (int i = 0; i < 16; i++) a1[i] = bb;
    }
    for (int k = 0; k < 26; k++) {
      float w = eW1[k * 128 + j];
      #pragma unroll
      for (int i = 0; i < 16; i++) a1[i] += xsf[(ns * 16 + i) * 26 + k] * w;
    }
    #pragma unroll
    for (int i = 0; i < 16; i++) hid2[ns * 16 + i][j] = silu_f(a1[i]);
    __syncthreads();
    float a2[16];
    {
      float bb = eb2[j];
      #pragma unroll
      for (int i = 0; i < 16; i++) a2[i] = bb;
    }
    for (int k = 0; k < 128; k++) {
      float w = eW2[k * 128 + j];
      #pragma unroll
      for (int i = 0; i < 16; i++) a2[i] += hid2[ns * 16 + i][k] * w;
    }
    #pragma unroll
    for (int i = 0; i < 16; i++) {
      int n = n0e + ns * 16 + i;
      h[(size_t)n * 128 + j] = a2[i];
      hb[(size_t)n * 128 + j] = (__bf16)a2[i];
    }
  }
}

// ---------------- zprep (layer 0 only): z1b, z2b; zeros aggH ----------------
__global__ __launch_bounds__(256) void zprep_kernel(
    const __bf16* __restrict__ hb, const float* __restrict__ b1,
    const __bf16* __restrict__ W1at, const __bf16* __restrict__ W1bt,
    __bf16* __restrict__ z1b, __bf16* __restrict__ z2b, float* __restrict__ aggH)
{
  __shared__ __bf16 s_n[64][136];
  int tid = threadIdx.x, n0 = blockIdx.x * 64;
  {
    int n = tid >> 2, t4 = tid & 3;
    const bf16x8* hr = (const bf16x8*)(hb + (size_t)(n0 + n) * 128);
    #pragma unroll
    for (int i = 0; i < 4; i++)
      *(bf16x8*)&s_n[n][t4 * 8 + 32 * i] = hr[t4 + 4 * i];
  }
  {
    float4 zz = make_float4(0.f, 0.f, 0.f, 0.f);
    float4* ap = (float4*)(aggH + (size_t)n0 * 256);
    for (int i = tid; i < 64 * 256 / 4; i += 256) ap[i] = zz;
  }
  __syncthreads();
  const int wv = tid >> 6, ln = tid & 63, lc = ln & 15, qd = ln >> 4;
  for (int cp = 0; cp < 2; cp++) {
    f32x4 aA[4][2], aB[4][2];
    #pragma unroll
    for (int nt = 0; nt < 2; nt++) {
      float bv = b1[cp * 128 + wv * 32 + nt * 16 + lc];
      #pragma unroll
      for (int mt = 0; mt < 4; mt++) {
        aA[mt][nt][0] = 0.f; aA[mt][nt][1] = 0.f;
        aA[mt][nt][2] = 0.f; aA[mt][nt][3] = 0.f;
        aB[mt][nt][0] = bv; aB[mt][nt][1] = bv;
        aB[mt][nt][2] = bv; aB[mt][nt][3] = bv;
      }
    }
    #pragma unroll
    for (int kt = 0; kt < 4; kt++) {
      bf16x8 af[4];
      #pragma unroll
      for (int mt = 0; mt < 4; mt++)
        af[mt] = *(const bf16x8*)&s_n[mt * 16 + lc][kt * 32 + qd * 8];
      bf16x8 bwA[2], bwB[2];
      #pragma unroll
      for (int nt = 0; nt < 2; nt++) {
        int c = cp * 128 + wv * 32 + nt * 16 + lc;
        bwA[nt] = *(const bf16x8*)(W1at + (size_t)c * 128 + kt * 32 + qd * 8);
        bwB[nt] = *(const bf16x8*)(W1bt + (size_t)c * 128 + kt * 32 + qd * 8);
      }
      #pragma unroll
      for (int mt = 0; mt < 4; mt++)
        #pragma unroll
        for (int nt = 0; nt < 2; nt++) {
          aA[mt][nt] = __builtin_amdgcn_mfma_f32_16x16x32_bf16(af[mt], bwA[nt], aA[mt][nt], 0, 0, 0);
          aB[mt][nt] = __builtin_amdgcn_mfma_f32_16x16x32_bf16(af[mt], bwB[nt], aB[mt][nt], 0, 0, 0);
        }
    }
    #pragma unroll
    for (int mt = 0; mt < 4; mt++)
      #pragma unroll
      for (int nt = 0; nt < 2; nt++) {
        int c = cp * 128 + wv * 32 + nt * 16 + lc;
        #pragma unroll
        for (int r = 0; r < 4; r++) {
          int n = n0 + mt * 16 + qd * 4 + r;
          z1b[(size_t)n * 256 + c] = (__bf16)aA[mt][nt][r];
          z2b[(size_t)n * 256 + c] = (__bf16)aB[mt][nt][r];
        }
      }
  }
}

// ---------------- fused message kernel v9: two-pass half-width s_hT ----------------
__global__ __launch_bounds__(256, 7) void msg_mfma_kernel(
    const __bf16* __restrict__ z1b, const __bf16* __restrict__ z2b,
    const __bf16* __restrict__ efb,
    const int* __restrict__ esrc, const int* __restrict__ edst,
    const __bf16* __restrict__ B2c, float* __restrict__ aggH)
{
  __shared__ __align__(16) __bf16 s_hT[128][70];   // 17920 B
  __shared__ __align__(16) __bf16 s_ef[TE][24];    // 3072 B
  __shared__ int s_src[TE];
  __shared__ int s_dst[TE];
  __shared__ unsigned int s_mask[2];

  int tid = threadIdx.x, e0 = blockIdx.x * TE;

  if (tid < TE) {
    int d = edst[e0 + tid];
    s_dst[tid] = d;
    int dp = (tid == 0) ? (d ^ 1) : edst[e0 + tid - 1];
    unsigned long long mb = __ballot(d != dp);
    if (tid == 0) { s_mask[0] = (unsigned int)mb; s_mask[1] = (unsigned int)(mb >> 32); }
  } else if (tid < 2 * TE) {
    s_src[tid - TE] = esrc[e0 + tid - TE];
  }
  {
    int e = tid >> 2, t4 = tid & 3;
    if (t4 < 2)
      *(bf16x8*)&s_ef[e][t4 * 8] =
          *(const bf16x8*)(efb + (size_t)(e0 + e) * 16 + t4 * 8);
  }
  __syncthreads();

  const int wv = tid >> 6, ln = tid & 63, lc = ln & 15, qd = ln >> 4;

  // identity B fragment: C[e][c] = A[e][c] + A[e][c+16] (z1[src]+z2[dst])
  bf16x8 bI;
  #pragma unroll
  for (int j = 0; j < 8; j++)
    bI[j] = (__bf16)((lc == (qd & 1) * 8 + j) ? 1.0f : 0.0f);

  // z row pointers: qd<2 supplies z1[src] k-halves, qd>=2 z2[dst]
  const __bf16* pz[4];
  #pragma unroll
  for (int mt = 0; mt < 4; mt++) {
    int m = mt * 16 + lc;
    int row = (qd < 2) ? s_src[m] : s_dst[m];
    pz[mt] = ((qd < 2) ? z1b : z2b) + (size_t)row * 256 + (qd & 1) * 8;
  }

  // ef A-fragments (rows = edges), reused across both passes
  bf16x8 aef[4];
  #pragma unroll
  for (int mt = 0; mt < 4; mt++)
    aef[mt] = *(const bf16x8*)&s_ef[mt * 16 + lc][(qd & 1) * 8];

  // scan-role constants: 2 threads per column, 32 rows each
  const int sj = tid & 127;
  const int srow0 = (tid >> 7) * 32;
  const unsigned int smask = __builtin_amdgcn_readfirstlane(s_mask[tid >> 7]);

  #pragma unroll
  for (int hf = 0; hf < 2; hf++) {
    if (hf) __syncthreads();   // protect s_hT until previous scan done

    #pragma unroll
    for (int nt = 0; nt < 2; nt++) {
      const int cb = hf * 128 + wv * 32 + nt * 16;
      bf16x8 bw = *(const bf16x8*)(B2c + (size_t)(cb + lc) * 32 + qd * 8);
      #pragma unroll
      for (int mt = 0; mt < 4; mt++) {
        bf16x8 az = *(const bf16x8*)(pz[mt] + cb);
        f32x4 z; z[0] = 0.f; z[1] = 0.f; z[2] = 0.f; z[3] = 0.f;
        f32x4 acc = __builtin_amdgcn_mfma_f32_16x16x32_bf16(az, bI, z, 0, 0, 0);
        acc = __builtin_amdgcn_mfma_f32_16x16x32_bf16(aef[mt], bw, acc, 0, 0, 0);
        bf16x2 p0, p1;
        p0[0] = (__bf16)silu_f(acc[0]); p0[1] = (__bf16)silu_f(acc[1]);
        p1[0] = (__bf16)silu_f(acc[2]); p1[1] = (__bf16)silu_f(acc[3]);
        __bf16* wp = &s_hT[wv * 32 + nt * 16 + lc][mt * 16 + qd * 4];
        *(bf16x2*)wp = p0;
        *(bf16x2*)(wp + 2) = p1;
      }
    }
    __syncthreads();

    // scan: 256 threads x (1 column half): col sj, rows [srow0, srow0+32)
    {
      const int gcol = hf * 128 + sj;
      float acc = 0.0f;
      int cur = s_dst[srow0];
      #pragma unroll 8
      for (int i = 0; i < 32; i += 2) {
        bf16x2 p = *(const bf16x2*)&s_hT[sj][srow0 + i];
        if (i > 0 && ((smask >> i) & 1u)) {
          atomicAdd(&aggH[(size_t)cur * 256 + gcol], acc);
          acc = 0.0f; cur = s_dst[srow0 + i];
        }
        acc += (float)p[0];
        if ((smask >> (i + 1)) & 1u) {
          atomicAdd(&aggH[(size_t)cur * 256 + gcol], acc);
          acc = 0.0f; cur = s_dst[srow0 + i + 1];
        }
        acc += (float)p[1];
      }
      atomicAdd(&aggH[(size_t)cur * 256 + gcol], acc);
    }
  }
}

// ---------------- fused node update MLP v4: 512 threads, 64 nodes + next-layer zprep ----------------
__global__ __launch_bounds__(512, 2) void upd_mfma_kernel(
    float* __restrict__ h, __bf16* __restrict__ hb,
    float* __restrict__ aggH, const float* __restrict__ degf,
    const __bf16* __restrict__ uW1ft, const float* __restrict__ b1,
    const float* __restrict__ b2u,
    const __bf16* __restrict__ uW2t, const float* __restrict__ b2,
    int do_z, const float* __restrict__ nb1,
    const __bf16* __restrict__ nW1at, const __bf16* __restrict__ nW1bt,
    __bf16* __restrict__ z1b, __bf16* __restrict__ z2b)
{
  __shared__ __bf16 s_u[64][392];    // [h(128) | agg(256)] + 8 pad
  __shared__ __bf16 s_uh[64][264];   // 256 hidden cols + 8 pad
  int tid = threadIdx.x, n0 = blockIdx.x * 64;
  {
    int n = tid >> 3, t8 = tid & 7;  // 8 threads per node
    const bf16x8* hr = (const bf16x8*)(hb + (size_t)(n0 + n) * 128);
    #pragma unroll
    for (int i = 0; i < 2; i++)
      *(bf16x8*)&s_u[n][t8 * 8 + 64 * i] = hr[t8 + 8 * i];
    const float* sr = aggH + (size_t)(n0 + n) * 256;
    #pragma unroll
    for (int i = 0; i < 4; i++) {
      int col = t8 * 8 + i * 64;
      float4 a = *(const float4*)(sr + col);
      float4 b = *(const float4*)(sr + col + 4);
      bf16x8 o;
      o[0] = (__bf16)a.x; o[1] = (__bf16)a.y; o[2] = (__bf16)a.z; o[3] = (__bf16)a.w;
      o[4] = (__bf16)b.x; o[5] = (__bf16)b.y; o[6] = (__bf16)b.z; o[7] = (__bf16)b.w;
      *(bf16x8*)&s_u[n][128 + col] = o;
    }
  }
  __syncthreads();
  const int wv = tid >> 6, ln = tid & 63, lc = ln & 15, qd = ln >> 4;  // wv 0..7

  float dg[4][4];
  #pragma unroll
  for (int mt = 0; mt < 4; mt++)
    #pragma unroll
    for (int r = 0; r < 4; r++)
      dg[mt][r] = degf[n0 + mt * 16 + qd * 4 + r];

  // ---- GEMM1: K=384, wave owns cols wv*32 + nt*16 + lc ----
  {
    f32x4 acc1[4][2];
    #pragma unroll
    for (int nt = 0; nt < 2; nt++) {
      int c = wv * 32 + nt * 16 + lc;
      float bv = b1[c];
      float b2uv = b2u[c];
      #pragma unroll
      for (int mt = 0; mt < 4; mt++)
        #pragma unroll
        for (int r = 0; r < 4; r++)
          acc1[mt][nt][r] = bv + dg[mt][r] * b2uv;
    }
    #pragma unroll
    for (int kt = 0; kt < 12; kt++) {
      bf16x8 af[4];
      #pragma unroll
      for (int mt = 0; mt < 4; mt++)
        af[mt] = *(const bf16x8*)&s_u[mt * 16 + lc][kt * 32 + qd * 8];
      bf16x8 bw[2];
      #pragma unroll
      for (int nt = 0; nt < 2; nt++)
        bw[nt] = *(const bf16x8*)(uW1ft +
                 (size_t)(wv * 32 + nt * 16 + lc) * 384 + kt * 32 + qd * 8);
      #pragma unroll
      for (int mt = 0; mt < 4; mt++)
        #pragma unroll
        for (int nt = 0; nt < 2; nt++)
          acc1[mt][nt] = __builtin_amdgcn_mfma_f32_16x16x32_bf16(af[mt], bw[nt], acc1[mt][nt], 0, 0, 0);
    }
    #pragma unroll
    for (int mt = 0; mt < 4; mt++)
      #pragma unroll
      for (int nt = 0; nt < 2; nt++) {
        int cc = wv * 32 + nt * 16 + lc;
        #pragma unroll
        for (int r = 0; r < 4; r++)
          s_uh[mt * 16 + qd * 4 + r][cc] = (__bf16)silu_f(acc1[mt][nt][r]);
      }
  }
  __syncthreads();

  // ---- GEMM2: K=256, wave owns output cols ow = wv*16 + lc ----
  const int ow = wv * 16 + lc;
  f32x4 acc2[4];
  {
    float bv = b2[ow];
    #pragma unroll
    for (int mt = 0; mt < 4; mt++) {
      acc2[mt][0] = bv; acc2[mt][1] = bv; acc2[mt][2] = bv; acc2[mt][3] = bv;
    }
  }
  #pragma unroll
  for (int kt = 0; kt < 8; kt++) {
    bf16x8 a2[4];
    #pragma unroll
    for (int mt = 0; mt < 4; mt++)
      a2[mt] = *(const bf16x8*)&s_uh[mt * 16 + lc][kt * 32 + qd * 8];
    bf16x8 b2w = *(const bf16x8*)(uW2t + (size_t)ow * 256 + kt * 32 + qd * 8);
    #pragma unroll
    for (int mt = 0; mt < 4; mt++)
      acc2[mt] = __builtin_amdgcn_mfma_f32_16x16x32_bf16(a2[mt], b2w, acc2[mt], 0, 0, 0);
  }

  // residual epilogue
  #pragma unroll
  for (int mt = 0; mt < 4; mt++)
    #pragma unroll
    for (int r = 0; r < 4; r++) {
      int n = n0 + mt * 16 + qd * 4 + r;
      float v = h[(size_t)n * 128 + ow] + acc2[mt][r];
      h[(size_t)n * 128 + ow] = v;
      hb[(size_t)n * 128 + ow] = (__bf16)v;
    }

  // ---- fused zprep for next layer ----
  if (do_z) {
    __syncthreads();
    {
      float4 zz = make_float4(0.f, 0.f, 0.f, 0.f);
      float4* ap = (float4*)(aggH + (size_t)n0 * 256);
      for (int i = tid; i < 64 * 256 / 4; i += 512) ap[i] = zz;
      int n = tid >> 3, t8 = tid & 7;
      const bf16x8* hr = (const bf16x8*)(hb + (size_t)(n0 + n) * 128);
      #pragma unroll
      for (int i = 0; i < 2; i++)
        *(bf16x8*)&s_u[n][t8 * 8 + 64 * i] = hr[t8 + 8 * i];
    }
    __syncthreads();
    f32x4 aA[4][2], aB[4][2];
    #pragma unroll
    for (int nt = 0; nt < 2; nt++) {
      float bv = nb1[wv * 32 + nt * 16 + lc];
      #pragma unroll
      for (int mt = 0; mt < 4; mt++) {
        aA[mt][nt][0] = 0.f; aA[mt][nt][1] = 0.f;
        aA[mt][nt][2] = 0.f; aA[mt][nt][3] = 0.f;
        aB[mt][nt][0] = bv; aB[mt][nt][1] = bv;
        aB[mt][nt][2] = bv; aB[mt][nt][3] = bv;
      }
    }
    #pragma unroll
    for (int kt = 0; kt < 4; kt++) {
      bf16x8 af[4];
      #pragma unroll
      for (int mt = 0; mt < 4; mt++)
        af[mt] = *(const bf16x8*)&s_u[mt * 16 + lc][kt * 32 + qd * 8];
      bf16x8 bwA[2], bwB[2];
      #pragma unroll
      for (int nt = 0; nt < 2; nt++) {
        int c = wv * 32 + nt * 16 + lc;
        bwA[nt] = *(const bf16x8*)(nW1at + (size_t)c * 128 + kt * 32 + qd * 8);
        bwB[nt] = *(const bf16x8*)(nW1bt + (size_t)c * 128 + kt * 32 + qd * 8);
      }
      #pragma unroll
      for (int mt = 0; mt < 4; mt++)
        #pragma unroll
        for (int nt = 0; nt < 2; nt++) {
          aA[mt][nt] = __builtin_amdgcn_mfma_f32_16x16x32_bf16(af[mt], bwA[nt], aA[mt][nt], 0, 0, 0);
          aB[mt][nt] = __builtin_amdgcn_mfma_f32_16x16x32_bf16(af[mt], bwB[nt], aB[mt][nt], 0, 0, 0);
        }
    }
    #pragma unroll
    for (int mt = 0; mt < 4; mt++)
      #pragma unroll
      for (int nt = 0; nt < 2; nt++) {
        int c = wv * 32 + nt * 16 + lc;
        #pragma unroll
        for (int r = 0; r < 4; r++) {
          int n = n0 + mt * 16 + qd * 4 + r;
          z1b[(size_t)n * 256 + c] = (__bf16)aA[mt][nt][r];
          z2b[(size_t)n * 256 + c] = (__bf16)aB[mt][nt][r];
        }
      }
  }
}

// ---------------- readout ----------------
__global__ __launch_bounds__(128) void readout_sum_kernel(
    const float* __restrict__ h, const int* __restrict__ batch,
    float* __restrict__ gsum, float* __restrict__ gcnt)
{
  int j = threadIdx.x;
  int n0 = blockIdx.x * 128;
  float acc = 0.f, cacc = 0.f;
  int cur = batch[n0];
  for (int i = 0; i < 128; i++) {
    int b = batch[n0 + i];
    if (b != cur) {
      atomicAdd(&gsum[cur * 128 + j], acc);
      if (j == 0) atomicAdd(&gcnt[cur], cacc);
      acc = 0.f; cacc = 0.f; cur = b;
    }
    acc += h[(size_t)(n0 + i) * 128 + j];
    cacc += 1.f;
  }
  atomicAdd(&gsum[cur * 128 + j], acc);
  if (j == 0) atomicAdd(&gcnt[cur], cacc);
}

__global__ __launch_bounds__(256) void readout_mlp_kernel(
    const float* __restrict__ gsum, const float* __restrict__ gcnt,
    const float* __restrict__ W1, const float* __restrict__ b1,
    const float* __restrict__ W2, const float* __restrict__ b2,
    float* __restrict__ out)
{
  __shared__ float g[8][128];
  __shared__ float hid[8][256];
  int tid = threadIdx.x;
  for (int i = tid; i < 8 * 128; i += 256) {
    int b = i >> 7, c = i & 127;
    g[b][c] = gsum[i] / fmaxf(gcnt[b], 1.0f);
  }
  __syncthreads();
  {
    float bb = b1[tid];
    float a[8];
    #pragma unroll
    for (int b = 0; b < 8; b++) a[b] = bb;
    for (int k = 0; k < 128; k++) {
      float w = W1[k * 256 + tid];
      #pragma unroll
      for (int b = 0; b < 8; b++) a[b] += g[b][k] * w;
    }
    #pragma unroll
    for (int b = 0; b < 8; b++) hid[b][tid] = silu_f(a[b]);
  }
  __syncthreads();
  int j = tid & 63, bg = tid >> 6;
  float a0 = b2[j], a1 = b2[j];
  for (int k = 0; k < 256; k++) {
    float w = W2[k * 64 + j];
    a0 += hid[bg * 2 + 0][k] * w;
    a1 += hid[bg * 2 + 1][k] * w;
  }
  out[(bg * 2 + 0) * 64 + j] = a0;
  out[(bg * 2 + 1) * 64 + j] = a1;
}

extern "C" void kernel_launch(void* const* d_in, const int* in_sizes, int n_in,
                              void* d_out, int out_size, void* d_ws, size_t ws_size,
                              hipStream_t stream) {
  const float* pos   = (const float*)d_in[0];
  const float* xfeat = (const float*)d_in[1];
  const int*   eidx  = (const int*)d_in[2];
  const int*   batch = (const int*)d_in[3];
  const float* eW1 = (const float*)d_in[4];
  const float* eb1 = (const float*)d_in[5];
  const float* eW2 = (const float*)d_in[6];
  const float* eb2 = (const float*)d_in[7];
  const float* mW1 = (const float*)d_in[8];
  const float* mb1 = (const float*)d_in[9];
  const float* mW2 = (const float*)d_in[10];
  const float* mb2 = (const float*)d_in[11];
  const float* uW1 = (const float*)d_in[12];
  const float* ub1 = (const float*)d_in[13];
  const float* uW2 = (const float*)d_in[14];
  const float* ub2 = (const float*)d_in[15];
  const float* rW1 = (const float*)d_in[16];
  const float* rb1 = (const float*)d_in[17];
  const float* rW2 = (const float*)d_in[18];
  const float* rb2 = (const float*)d_in[19];

  const int* srcI = eidx;
  const int* dstI = eidx + NEDGES;

  char* base = (char*)d_ws;
  float* h    = (float*)base;  base += (size_t)NATOMS * 128 * 4;
  float* aggH = (float*)base;  base += (size_t)NATOMS * 256 * 4;
  __bf16* z1b = (__bf16*)base; base += (size_t)NATOMS * 256 * 2;
  __bf16* z2b = (__bf16*)base; base += (size_t)NATOMS * 256 * 2;
  __bf16* hb  = (__bf16*)base; base += (size_t)NATOMS * 128 * 2;
  __bf16* efb = (__bf16*)base; base += (size_t)NEDGES * 16 * 2;
  __bf16* W1at = (__bf16*)base; base += (size_t)NLAYERS * 256 * 128 * 2;
  __bf16* W1bt = (__bf16*)base; base += (size_t)NLAYERS * 256 * 128 * 2;
  __bf16* B2c  = (__bf16*)base; base += (size_t)NLAYERS * 256 * 32 * 2;
  __bf16* uW1ft = (__bf16*)base; base += (size_t)NLAYERS * 256 * 384 * 2;
  __bf16* uW2t = (__bf16*)base; base += (size_t)NLAYERS * 128 * 256 * 2;
  float* b2u  = (float*)base;  base += (size_t)NLAYERS * 256 * 4;
  float* degf = (float*)base;  base += (size_t)NATOMS * 4;
  float* gsum = (float*)base;  base += 8 * 128 * 4;
  float* gcnt = (float*)base;  base += 8 * 4;
  int* counts = (int*)base;    base += (size_t)NATOMS * 4;
  int* cursor = (int*)base;    base += (size_t)NATOMS * 4;
  int* esrc   = (int*)base;    base += (size_t)NEDGES * 4;
  int* edst   = (int*)base;    base += (size_t)NEDGES * 4;

  // counts must be zeroed before front_kernel's hist section
  hipMemsetAsync(counts, 0, NATOMS * sizeof(int), stream);

  // merged front: weight prep + dst histogram + embedding
  front_kernel<<<NB_PREP + NB_HIST + NB_EMB, 256, 0, stream>>>(
      mW1, mW2, uW1, uW2, mb2, W1at, W1bt, B2c, uW1ft, uW2t, b2u,
      dstI, counts, xfeat, eW1, eb1, eW2, eb2, h, hb);

  scan_kernel<<<1, 1024, 0, stream>>>(counts, cursor, degf);
  scatter_rbf_kernel<<<NEDGES / 256, 256, 0, stream>>>(
      srcI, dstI, cursor, pos, esrc, edst, efb);

  // zprep for layer 0 (also zeros aggH)
  zprep_kernel<<<NATOMS / 64, 256, 0, stream>>>(
      hb, mb1, W1at, W1bt, z1b, z2b, aggH);

  for (int l = 0; l < NLAYERS; l++) {
    int ln = (l < NLAYERS - 1) ? (l + 1) : l;
    msg_mfma_kernel<<<NEDGES / TE, 256, 0, stream>>>(
        z1b, z2b, efb, esrc, edst,
        B2c + (size_t)l * 256 * 32, aggH);
    upd_mfma_kernel<<<NATOMS / 64, 512, 0, stream>>>(
        h, hb, aggH, degf,
        uW1ft + (size_t)l * 256 * 384, ub1 + (size_t)l * 256,
        b2u + (size_t)l * 256,
        uW2t + (size_t)l * 128 * 256, ub2 + (size_t)l * 128,
        (l < NLAYERS - 1) ? 1 : 0,
        mb1 + (size_t)ln * 256,
        W1at + (size_t)ln * 256 * 128, W1bt + (size_t)ln * 256 * 128,
        z1b, z2b);
  }

  hipMemsetAsync(gsum, 0, (8 * 128 + 8) * sizeof(float), stream);
  readout_sum_kernel<<<NATOMS / 128, 128, 0, stream>>>(h, batch, gsum, gcnt);
  readout_mlp_kernel<<<1, 256, 0, stream>>>(gsum, gcnt, rW1, rb1, rW2, rb2,
                                            (float*)d_out);
}

// Round 4
// 578.588 us; speedup vs baseline: 1.2255x; 1.0081x over previous
//
#include <hip/hip_runtime.h>
#include <math.h>

#define NATOMS 16384
#define NEDGES 524288
#define NLAYERS 4
#define TE 64      // edges per block in msg kernel

typedef __bf16 bf16x8 __attribute__((ext_vector_type(8)));
typedef __bf16 bf16x4 __attribute__((ext_vector_type(4)));
typedef __bf16 bf16x2 __attribute__((ext_vector_type(2)));
typedef float f32x4 __attribute__((ext_vector_type(4)));

// fast silu: x * rcp(1+exp(-x))
__device__ __forceinline__ float silu_f(float x) {
  return x * __builtin_amdgcn_rcpf(1.0f + __expf(-x));
}

// ---------------- CSR preprocessing ----------------
__global__ __launch_bounds__(1024) void scan_kernel(
    const int* __restrict__ counts, int* __restrict__ cursor,
    float* __restrict__ degf)
{
  __shared__ int s_tot[1024];
  int tid = threadIdx.x;
  int v[16];
  {
    const int4* cp = (const int4*)(counts + tid * 16);
    int4 a = cp[0], b = cp[1], c = cp[2], d = cp[3];
    v[0]=a.x; v[1]=a.y; v[2]=a.z; v[3]=a.w;
    v[4]=b.x; v[5]=b.y; v[6]=b.z; v[7]=b.w;
    v[8]=c.x; v[9]=c.y; v[10]=c.z; v[11]=c.w;
    v[12]=d.x; v[13]=d.y; v[14]=d.z; v[15]=d.w;
  }
  int tot = 0;
  #pragma unroll
  for (int i = 0; i < 16; i++) tot += v[i];
  s_tot[tid] = tot;
  __syncthreads();
  for (int off = 1; off < 1024; off <<= 1) {
    int t = (tid >= off) ? s_tot[tid - off] : 0;
    __syncthreads();
    s_tot[tid] += t;
    __syncthreads();
  }
  int run = s_tot[tid] - tot;   // exclusive prefix
  #pragma unroll
  for (int i = 0; i < 16; i++) {
    cursor[tid * 16 + i] = run;
    degf[tid * 16 + i] = (float)v[i];
    run += v[i];
  }
}

// scatter + RBF fused: each edge computes its sorted slot p, writes esrc/edst
// AND its RBF features directly to efb[p].
__global__ __launch_bounds__(256) void scatter_rbf_kernel(
    const int* __restrict__ src, const int* __restrict__ dst,
    int* __restrict__ cursor, const float* __restrict__ pos,
    int* __restrict__ esrc, int* __restrict__ edst,
    __bf16* __restrict__ efb)
{
  int e = blockIdx.x * 256 + threadIdx.x;
  int s = src[e], d = dst[e];
  int p = atomicAdd(&cursor[d], 1);
  esrc[p] = s;
  edst[p] = d;
  float dx = pos[d * 3 + 0] - pos[s * 3 + 0];
  float dy = pos[d * 3 + 1] - pos[s * 3 + 1];
  float dz = pos[d * 3 + 2] - pos[s * 3 + 2];
  float dist = sqrtf(dx * dx + dy * dy + dz * dz + 1e-12f);
  float env = (dist < 10.0f)
                  ? 0.5f * (cosf(3.14159265358979f * dist * 0.1f) + 1.0f)
                  : 0.0f;
  bf16x8 o0, o1;
  #pragma unroll
  for (int i = 0; i < 16; i++) {
    float c = (10.0f / 15.0f) * (float)i;
    float t = dist - c;
    float v = env * __expf(-t * t * 1.28f);
    if (i < 8) o0[i] = (__bf16)v; else o1[i - 8] = (__bf16)v;
  }
  *(bf16x8*)(efb + (size_t)p * 16 + 0) = o0;
  *(bf16x8*)(efb + (size_t)p * 16 + 8) = o1;
}

// ---------------- merged front kernel v2 ----------------
// prep: LDS-tiled 64x64 transposes (coalesced both sides),
// 16-row-slab fusion GEMM (16-way ILP), 32-node embed blocks.
#define NB_PL   50
#define NB_PREP (NB_PL * NLAYERS)
#define NB_HIST (NEDGES / 256)
#define NB_EMB  (NATOMS / 32)

__global__ __launch_bounds__(256) void front_kernel(
    const float* __restrict__ mW1, const float* __restrict__ mW2,
    const float* __restrict__ uW1, const float* __restrict__ uW2,
    const float* __restrict__ mb2,
    __bf16* __restrict__ W1at, __bf16* __restrict__ W1bt,
    __bf16* __restrict__ B2c, __bf16* __restrict__ uW1ft,
    __bf16* __restrict__ uW2t, float* __restrict__ b2u,
    const int* __restrict__ dstI, int* __restrict__ counts,
    const float* __restrict__ x, const float* __restrict__ eW1,
    const float* __restrict__ eb1, const float* __restrict__ eW2,
    const float* __restrict__ eb2, float* __restrict__ h,
    __bf16* __restrict__ hb)
{
  __shared__ __align__(16) char smem[19712];
  int bxf = blockIdx.x, tid = threadIdx.x;

  if (bxf < NB_PREP) {
    int l = bxf / NB_PL;
    int bx = bxf - l * NB_PL;
    if (bx < 16) {
      // W1at / W1bt: transpose 64x64 tiles of mW1 rows [0,256)
      float (*tile)[65] = (float(*)[65])smem;
      int tt = bx & 7;
      int row0 = ((tt >> 2) * 64) + ((bx < 8) ? 0 : 128);   // source k-row
      int col0 = (tt & 3) * 64;                             // source col (c)
      const float* Sp = mW1 + (size_t)l * (272 * 256) + (size_t)row0 * 256 + col0;
      __bf16* Dq = ((bx < 8) ? W1at : W1bt) + (size_t)l * (256 * 128);
      int dro = (bx < 8) ? row0 : row0 - 128;
      int c = tid & 63, r4 = tid >> 6;
      #pragma unroll
      for (int i = 0; i < 16; i++)
        tile[r4 + i * 4][c] = Sp[(size_t)(r4 + i * 4) * 256 + c];
      __syncthreads();
      #pragma unroll
      for (int i = 0; i < 16; i++) {
        int dr = r4 + i * 4;
        Dq[(size_t)(col0 + dr) * 128 + dro + c] = (__bf16)tile[c][dr];
      }
    } else if (bx == 16) {
      // B2c: rows 256..271 of mW1 -> [c][k] with zero pad to k=32
      float (*t3)[257] = (float(*)[257])smem;
      const float* Sp = mW1 + (size_t)l * (272 * 256) + 256 * 256;
      #pragma unroll
      for (int i = 0; i < 16; i++) t3[i][tid] = Sp[i * 256 + tid];
      __syncthreads();
      __bf16* Dp = B2c + (size_t)l * (256 * 32) + (size_t)tid * 32;
      #pragma unroll
      for (int g = 0; g < 4; g++) {
        bf16x8 o;
        #pragma unroll
        for (int j2 = 0; j2 < 8; j2++) {
          int k = g * 8 + j2;
          o[j2] = (__bf16)((k < 16) ? t3[k][tid] : 0.0f);
        }
        *(bf16x8*)(Dp + g * 8) = o;
      }
    } else if (bx < 25) {
      // uW1ft copy part (k<128): transpose 64x64 tiles of uW1
      float (*tile)[65] = (float(*)[65])smem;
      int tt = bx - 17;
      int row0 = (tt >> 2) * 64;         // k
      int col0 = (tt & 3) * 64;          // n
      const float* Sp = uW1 + (size_t)l * 65536 + (size_t)row0 * 256 + col0;
      __bf16* Dq = uW1ft + (size_t)l * (256 * 384);
      int c = tid & 63, r4 = tid >> 6;
      #pragma unroll
      for (int i = 0; i < 16; i++)
        tile[r4 + i * 4][c] = Sp[(size_t)(r4 + i * 4) * 256 + c];
      __syncthreads();
      #pragma unroll
      for (int i = 0; i < 16; i++) {
        int dr = r4 + i * 4;
        Dq[(size_t)(col0 + dr) * 384 + row0 + c] = (__bf16)tile[c][dr];
      }
    } else if (bx < 41) {
      // fusion slab: F[r0+r][n] = sum_j mW2[r0+r][j] * uW1[128+j][n]
      float (*sA)[128] = (float(*)[128])smem;
      int r0 = (bx - 25) * 16;
      const float* Ap = mW2 + (size_t)(l * 256 + r0) * 128;
      #pragma unroll
      for (int i = 0; i < 8; i++) {
        int idx = i * 256 + tid;
        ((float*)smem)[idx] = Ap[idx];
      }
      __syncthreads();
      const float* Bp = uW1 + (size_t)l * 65536 + 128 * 256 + tid;
      float acc[16];
      #pragma unroll
      for (int r = 0; r < 16; r++) acc[r] = 0.0f;
      for (int k = 0; k < 128; k++) {
        float b = Bp[(size_t)k * 256];
        #pragma unroll
        for (int r = 0; r < 16; r++) acc[r] += sA[r][k] * b;
      }
      __bf16* Dp = uW1ft + (size_t)l * (256 * 384) + (size_t)tid * 384 + 128 + r0;
      bf16x8 o0, o1;
      #pragma unroll
      for (int r = 0; r < 8; r++) { o0[r] = (__bf16)acc[r]; o1[r] = (__bf16)acc[8 + r]; }
      *(bf16x8*)Dp = o0;
      *(bf16x8*)(Dp + 8) = o1;
    } else if (bx < 49) {
      // uW2t: transpose 64x64 tiles of uW2 (256x128)
      float (*tile)[65] = (float(*)[65])smem;
      int tt = bx - 41;
      int row0 = (tt >> 1) * 64;     // k in [0,256)
      int col0 = (tt & 1) * 64;      // n in [0,128)
      const float* Sp = uW2 + (size_t)l * (256 * 128) + (size_t)row0 * 128 + col0;
      __bf16* Dq = uW2t + (size_t)l * (128 * 256);
      int c = tid & 63, r4 = tid >> 6;
      #pragma unroll
      for (int i = 0; i < 16; i++)
        tile[r4 + i * 4][c] = Sp[(size_t)(r4 + i * 4) * 128 + c];
      __syncthreads();
      #pragma unroll
      for (int i = 0; i < 16; i++) {
        int dr = r4 + i * 4;
        Dq[(size_t)(col0 + dr) * 256 + row0 + c] = (__bf16)tile[c][dr];
      }
    } else {
      // b2u[c] = sum_j mb2[j] * uW1[128+j][c]
      int cc = tid;
      float acc = 0.0f;
      for (int j2 = 0; j2 < 128; j2++)
        acc += mb2[l * 128 + j2] * uW1[(size_t)l * 65536 + (size_t)(128 + j2) * 256 + cc];
      b2u[l * 256 + cc] = acc;
    }
  } else if (bxf < NB_PREP + NB_HIST) {
    int e = (bxf - NB_PREP) * 256 + tid;
    atomicAdd(&counts[dstI[e]], 1);
  } else {
    // embedding: 32 nodes per block, 16 accumulators per thread
    int nb = bxf - (NB_PREP + NB_HIST);
    int n0e = nb * 32;
    float* xsf = (float*)smem;                               // [32][26]
    float (*hid2)[128] = (float(*)[128])(smem + 32 * 26 * 4);
    for (int i = tid; i < 32 * 26; i += 256)
      xsf[i] = x[(size_t)n0e * 26 + i];
    __syncthreads();
    int j = tid & 127, ns = tid >> 7;
    float a1[16];
    {
      float bb = eb1[j];
      #pragma unroll
      for (int i = 0; i < 16; i++) a1[i] = bb;
    }
    for (int k = 0; k < 26; k++) {
      float w = eW1[k * 128 + j];
      #pragma unroll
      for (int i = 0; i < 16; i++) a1[i] += xsf[(ns * 16 + i) * 26 + k] * w;
    }
    #pragma unroll
    for (int i = 0; i < 16; i++) hid2[ns * 16 + i][j] = silu_f(a1[i]);
    __syncthreads();
    float a2[16];
    {
      float bb = eb2[j];
      #pragma unroll
      for (int i = 0; i < 16; i++) a2[i] = bb;
    }
    for (int k = 0; k < 128; k++) {
      float w = eW2[k * 128 + j];
      #pragma unroll
      for (int i = 0; i < 16; i++) a2[i] += hid2[ns * 16 + i][k] * w;
    }
    #pragma unroll
    for (int i = 0; i < 16; i++) {
      int n = n0e + ns * 16 + i;
      h[(size_t)n * 128 + j] = a2[i];
      hb[(size_t)n * 128 + j] = (__bf16)a2[i];
    }
  }
}

// ---------------- zprep (layer 0 only): z1b, z2b; zeros aggH ----------------
__global__ __launch_bounds__(256) void zprep_kernel(
    const __bf16* __restrict__ hb, const float* __restrict__ b1,
    const __bf16* __restrict__ W1at, const __bf16* __restrict__ W1bt,
    __bf16* __restrict__ z1b, __bf16* __restrict__ z2b, float* __restrict__ aggH)
{
  __shared__ __bf16 s_n[64][136];
  int tid = threadIdx.x, n0 = blockIdx.x * 64;
  {
    int n = tid >> 2, t4 = tid & 3;
    const bf16x8* hr = (const bf16x8*)(hb + (size_t)(n0 + n) * 128);
    #pragma unroll
    for (int i = 0; i < 4; i++)
      *(bf16x8*)&s_n[n][t4 * 8 + 32 * i] = hr[t4 + 4 * i];
  }
  {
    float4 zz = make_float4(0.f, 0.f, 0.f, 0.f);
    float4* ap = (float4*)(aggH + (size_t)n0 * 256);
    for (int i = tid; i < 64 * 256 / 4; i += 256) ap[i] = zz;
  }
  __syncthreads();
  const int wv = tid >> 6, ln = tid & 63, lc = ln & 15, qd = ln >> 4;
  for (int cp = 0; cp < 2; cp++) {
    f32x4 aA[4][2], aB[4][2];
    #pragma unroll
    for (int nt = 0; nt < 2; nt++) {
      float bv = b1[cp * 128 + wv * 32 + nt * 16 + lc];
      #pragma unroll
      for (int mt = 0; mt < 4; mt++) {
        aA[mt][nt][0] = 0.f; aA[mt][nt][1] = 0.f;
        aA[mt][nt][2] = 0.f; aA[mt][nt][3] = 0.f;
        aB[mt][nt][0] = bv; aB[mt][nt][1] = bv;
        aB[mt][nt][2] = bv; aB[mt][nt][3] = bv;
      }
    }
    #pragma unroll
    for (int kt = 0; kt < 4; kt++) {
      bf16x8 af[4];
      #pragma unroll
      for (int mt = 0; mt < 4; mt++)
        af[mt] = *(const bf16x8*)&s_n[mt * 16 + lc][kt * 32 + qd * 8];
      bf16x8 bwA[2], bwB[2];
      #pragma unroll
      for (int nt = 0; nt < 2; nt++) {
        int c = cp * 128 + wv * 32 + nt * 16 + lc;
        bwA[nt] = *(const bf16x8*)(W1at + (size_t)c * 128 + kt * 32 + qd * 8);
        bwB[nt] = *(const bf16x8*)(W1bt + (size_t)c * 128 + kt * 32 + qd * 8);
      }
      #pragma unroll
      for (int mt = 0; mt < 4; mt++)
        #pragma unroll
        for (int nt = 0; nt < 2; nt++) {
          aA[mt][nt] = __builtin_amdgcn_mfma_f32_16x16x32_bf16(af[mt], bwA[nt], aA[mt][nt], 0, 0, 0);
          aB[mt][nt] = __builtin_amdgcn_mfma_f32_16x16x32_bf16(af[mt], bwB[nt], aB[mt][nt], 0, 0, 0);
        }
    }
    #pragma unroll
    for (int mt = 0; mt < 4; mt++)
      #pragma unroll
      for (int nt = 0; nt < 2; nt++) {
        int c = cp * 128 + wv * 32 + nt * 16 + lc;
        #pragma unroll
        for (int r = 0; r < 4; r++) {
          int n = n0 + mt * 16 + qd * 4 + r;
          z1b[(size_t)n * 256 + c] = (__bf16)aA[mt][nt][r];
          z2b[(size_t)n * 256 + c] = (__bf16)aB[mt][nt][r];
        }
      }
  }
}

// ---------------- fused message kernel v10 ----------------
// v9 + LDS trimmed to 19976B (8 blocks/CU = 32 waves, the HW cap):
// s_hT pad 70->68 (keeps 8B alignment; b64 stores), s_ef [64][24]->[64][16].
// Scan processes 4 rows/iter with one uniform boundary test (boundaries
// are sparse ~3/block and wave-uniform) -> ~2x less scan VALU.
__global__ __launch_bounds__(256, 8) void msg_mfma_kernel(
    const __bf16* __restrict__ z1b, const __bf16* __restrict__ z2b,
    const __bf16* __restrict__ efb,
    const int* __restrict__ esrc, const int* __restrict__ edst,
    const __bf16* __restrict__ B2c, float* __restrict__ aggH)
{
  __shared__ __align__(16) __bf16 s_hT[128][68];   // 17408 B
  __shared__ __align__(16) __bf16 s_ef[TE][16];    // 2048 B
  __shared__ int s_src[TE];
  __shared__ int s_dst[TE];
  __shared__ unsigned int s_mask[2];

  int tid = threadIdx.x, e0 = blockIdx.x * TE;

  if (tid < TE) {
    int d = edst[e0 + tid];
    s_dst[tid] = d;
    int dp = (tid == 0) ? (d ^ 1) : edst[e0 + tid - 1];
    unsigned long long mb = __ballot(d != dp);
    if (tid == 0) { s_mask[0] = (unsigned int)mb; s_mask[1] = (unsigned int)(mb >> 32); }
  } else if (tid < 2 * TE) {
    s_src[tid - TE] = esrc[e0 + tid - TE];
  }
  {
    int e = tid >> 2, t4 = tid & 3;
    if (t4 < 2)
      *(bf16x8*)&s_ef[e][t4 * 8] =
          *(const bf16x8*)(efb + (size_t)(e0 + e) * 16 + t4 * 8);
  }
  __syncthreads();

  const int wv = tid >> 6, ln = tid & 63, lc = ln & 15, qd = ln >> 4;

  // identity B fragment: C[e][c] = A[e][c] + A[e][c+16] (z1[src]+z2[dst])
  bf16x8 bI;
  #pragma unroll
  for (int j = 0; j < 8; j++)
    bI[j] = (__bf16)((lc == (qd & 1) * 8 + j) ? 1.0f : 0.0f);

  // z row pointers: qd<2 supplies z1[src] k-halves, qd>=2 z2[dst]
  const __bf16* pz[4];
  #pragma unroll
  for (int mt = 0; mt < 4; mt++) {
    int m = mt * 16 + lc;
    int row = (qd < 2) ? s_src[m] : s_dst[m];
    pz[mt] = ((qd < 2) ? z1b : z2b) + (size_t)row * 256 + (qd & 1) * 8;
  }

  // ef A-fragments (rows = edges), reused across both passes
  bf16x8 aef[4];
  #pragma unroll
  for (int mt = 0; mt < 4; mt++)
    aef[mt] = *(const bf16x8*)&s_ef[mt * 16 + lc][(qd & 1) * 8];

  // scan-role constants: 2 threads per column, 32 rows each
  const int sj = tid & 127;
  const int srow0 = (tid >> 7) * 32;
  const unsigned int smask = __builtin_amdgcn_readfirstlane(s_mask[tid >> 7]);

  #pragma unroll
  for (int hf = 0; hf < 2; hf++) {
    if (hf) __syncthreads();   // protect s_hT until previous scan done

    #pragma unroll
    for (int nt = 0; nt < 2; nt++) {
      const int cb = hf * 128 + wv * 32 + nt * 16;
      bf16x8 bw = *(const bf16x8*)(B2c + (size_t)(cb + lc) * 32 + qd * 8);
      #pragma unroll
      for (int mt = 0; mt < 4; mt++) {
        bf16x8 az = *(const bf16x8*)(pz[mt] + cb);
        f32x4 z; z[0] = 0.f; z[1] = 0.f; z[2] = 0.f; z[3] = 0.f;
        f32x4 acc = __builtin_amdgcn_mfma_f32_16x16x32_bf16(az, bI, z, 0, 0, 0);
        acc = __builtin_amdgcn_mfma_f32_16x16x32_bf16(aef[mt], bw, acc, 0, 0, 0);
        bf16x4 pv;
        pv[0] = (__bf16)silu_f(acc[0]); pv[1] = (__bf16)silu_f(acc[1]);
        pv[2] = (__bf16)silu_f(acc[2]); pv[3] = (__bf16)silu_f(acc[3]);
        *(bf16x4*)&s_hT[wv * 32 + nt * 16 + lc][mt * 16 + qd * 4] = pv;
      }
    }
    __syncthreads();

    // scan: 256 threads x (1 column half): col sj, rows [srow0, srow0+32)
    // 4 rows per iter; uniform fast path when no boundary in the chunk.
    {
      const int gcol = hf * 128 + sj;
      float acc = 0.0f;
      int cur = s_dst[srow0];
      #pragma unroll
      for (int i = 0; i < 32; i += 4) {
        unsigned int bm = (smask >> i) & 0xFu;
        if (i == 0) bm &= 0xEu;   // never flush before the window's first row
        bf16x4 p = *(const bf16x4*)&s_hT[sj][srow0 + i];
        if (bm == 0u) {
          acc += ((float)p[0] + (float)p[1]) + ((float)p[2] + (float)p[3]);
        } else {
          #pragma unroll
          for (int r = 0; r < 4; r++) {
            if ((bm >> r) & 1u) {
              atomicAdd(&aggH[(size_t)cur * 256 + gcol], acc);
              acc = 0.0f; cur = s_dst[srow0 + i + r];
            }
            acc += (float)p[r];
          }
        }
      }
      atomicAdd(&aggH[(size_t)cur * 256 + gcol], acc);
    }
  }
}

// ---------------- fused node update MLP v4: 512 threads, 64 nodes + next-layer zprep ----------------
__global__ __launch_bounds__(512, 2) void upd_mfma_kernel(
    float* __restrict__ h, __bf16* __restrict__ hb,
    float* __restrict__ aggH, const float* __restrict__ degf,
    const __bf16* __restrict__ uW1ft, const float* __restrict__ b1,
    const float* __restrict__ b2u,
    const __bf16* __restrict__ uW2t, const float* __restrict__ b2,
    int do_z, const float* __restrict__ nb1,
    const __bf16* __restrict__ nW1at, const __bf16* __restrict__ nW1bt,
    __bf16* __restrict__ z1b, __bf16* __restrict__ z2b)
{
  __shared__ __bf16 s_u[64][392];    // [h(128) | agg(256)] + 8 pad
  __shared__ __bf16 s_uh[64][264];   // 256 hidden cols + 8 pad
  int tid = threadIdx.x, n0 = blockIdx.x * 64;
  {
    int n = tid >> 3, t8 = tid & 7;  // 8 threads per node
    const bf16x8* hr = (const bf16x8*)(hb + (size_t)(n0 + n) * 128);
    #pragma unroll
    for (int i = 0; i < 2; i++)
      *(bf16x8*)&s_u[n][t8 * 8 + 64 * i] = hr[t8 + 8 * i];
    const float* sr = aggH + (size_t)(n0 + n) * 256;
    #pragma unroll
    for (int i = 0; i < 4; i++) {
      int col = t8 * 8 + i * 64;
      float4 a = *(const float4*)(sr + col);
      float4 b = *(const float4*)(sr + col + 4);
      bf16x8 o;
      o[0] = (__bf16)a.x; o[1] = (__bf16)a.y; o[2] = (__bf16)a.z; o[3] = (__bf16)a.w;
      o[4] = (__bf16)b.x; o[5] = (__bf16)b.y; o[6] = (__bf16)b.z; o[7] = (__bf16)b.w;
      *(bf16x8*)&s_u[n][128 + col] = o;
    }
  }
  __syncthreads();
  const int wv = tid >> 6, ln = tid & 63, lc = ln & 15, qd = ln >> 4;  // wv 0..7

  float dg[4][4];
  #pragma unroll
  for (int mt = 0; mt < 4; mt++)
    #pragma unroll
    for (int r = 0; r < 4; r++)
      dg[mt][r] = degf[n0 + mt * 16 + qd * 4 + r];

  // ---- GEMM1: K=384, wave owns cols wv*32 + nt*16 + lc ----
  {
    f32x4 acc1[4][2];
    #pragma unroll
    for (int nt = 0; nt < 2; nt++) {
      int c = wv * 32 + nt * 16 + lc;
      float bv = b1[c];
      float b2uv = b2u[c];
      #pragma unroll
      for (int mt = 0; mt < 4; mt++)
        #pragma unroll
        for (int r = 0; r < 4; r++)
          acc1[mt][nt][r] = bv + dg[mt][r] * b2uv;
    }
    #pragma unroll
    for (int kt = 0; kt < 12; kt++) {
      bf16x8 af[4];
      #pragma unroll
      for (int mt = 0; mt < 4; mt++)
        af[mt] = *(const bf16x8*)&s_u[mt * 16 + lc][kt * 32 + qd * 8];
      bf16x8 bw[2];
      #pragma unroll
      for (int nt = 0; nt < 2; nt++)
        bw[nt] = *(const bf16x8*)(uW1ft +
                 (size_t)(wv * 32 + nt * 16 + lc) * 384 + kt * 32 + qd * 8);
      #pragma unroll
      for (int mt = 0; mt < 4; mt++)
        #pragma unroll
        for (int nt = 0; nt < 2; nt++)
          acc1[mt][nt] = __builtin_amdgcn_mfma_f32_16x16x32_bf16(af[mt], bw[nt], acc1[mt][nt], 0, 0, 0);
    }
    #pragma unroll
    for (int mt = 0; mt < 4; mt++)
      #pragma unroll
      for (int nt = 0; nt < 2; nt++) {
        int cc = wv * 32 + nt * 16 + lc;
        #pragma unroll
        for (int r = 0; r < 4; r++)
          s_uh[mt * 16 + qd * 4 + r][cc] = (__bf16)silu_f(acc1[mt][nt][r]);
      }
  }
  __syncthreads();

  // ---- GEMM2: K=256, wave owns output cols ow = wv*16 + lc ----
  const int ow = wv * 16 + lc;
  f32x4 acc2[4];
  {
    float bv = b2[ow];
    #pragma unroll
    for (int mt = 0; mt < 4; mt++) {
      acc2[mt][0] = bv; acc2[mt][1] = bv; acc2[mt][2] = bv; acc2[mt][3] = bv;
    }
  }
  #pragma unroll
  for (int kt = 0; kt < 8; kt++) {
    bf16x8 a2[4];
    #pragma unroll
    for (int mt = 0; mt < 4; mt++)
      a2[mt] = *(const bf16x8*)&s_uh[mt * 16 + lc][kt * 32 + qd * 8];
    bf16x8 b2w = *(const bf16x8*)(uW2t + (size_t)ow * 256 + kt * 32 + qd * 8);
    #pragma unroll
    for (int mt = 0; mt < 4; mt++)
      acc2[mt] = __builtin_amdgcn_mfma_f32_16x16x32_bf16(a2[mt], b2w, acc2[mt], 0, 0, 0);
  }

  // residual epilogue
  #pragma unroll
  for (int mt = 0; mt < 4; mt++)
    #pragma unroll
    for (int r = 0; r < 4; r++) {
      int n = n0 + mt * 16 + qd * 4 + r;
      float v = h[(size_t)n * 128 + ow] + acc2[mt][r];
      h[(size_t)n * 128 + ow] = v;
      hb[(size_t)n * 128 + ow] = (__bf16)v;
    }

  // ---- fused zprep for next layer ----
  if (do_z) {
    __syncthreads();
    {
      float4 zz = make_float4(0.f, 0.f, 0.f, 0.f);
      float4* ap = (float4*)(aggH + (size_t)n0 * 256);
      for (int i = tid; i < 64 * 256 / 4; i += 512) ap[i] = zz;
      int n = tid >> 3, t8 = tid & 7;
      const bf16x8* hr = (const bf16x8*)(hb + (size_t)(n0 + n) * 128);
      #pragma unroll
      for (int i = 0; i < 2; i++)
        *(bf16x8*)&s_u[n][t8 * 8 + 64 * i] = hr[t8 + 8 * i];
    }
    __syncthreads();
    f32x4 aA[4][2], aB[4][2];
    #pragma unroll
    for (int nt = 0; nt < 2; nt++) {
      float bv = nb1[wv * 32 + nt * 16 + lc];
      #pragma unroll
      for (int mt = 0; mt < 4; mt++) {
        aA[mt][nt][0] = 0.f; aA[mt][nt][1] = 0.f;
        aA[mt][nt][2] = 0.f; aA[mt][nt][3] = 0.f;
        aB[mt][nt][0] = bv; aB[mt][nt][1] = bv;
        aB[mt][nt][2] = bv; aB[mt][nt][3] = bv;
      }
    }
    #pragma unroll
    for (int kt = 0; kt < 4; kt++) {
      bf16x8 af[4];
      #pragma unroll
      for (int mt = 0; mt < 4; mt++)
        af[mt] = *(const bf16x8*)&s_u[mt * 16 + lc][kt * 32 + qd * 8];
      bf16x8 bwA[2], bwB[2];
      #pragma unroll
      for (int nt = 0; nt < 2; nt++) {
        int c = wv * 32 + nt * 16 + lc;
        bwA[nt] = *(const bf16x8*)(nW1at + (size_t)c * 128 + kt * 32 + qd * 8);
        bwB[nt] = *(const bf16x8*)(nW1bt + (size_t)c * 128 + kt * 32 + qd * 8);
      }
      #pragma unroll
      for (int mt = 0; mt < 4; mt++)
        #pragma unroll
        for (int nt = 0; nt < 2; nt++) {
          aA[mt][nt] = __builtin_amdgcn_mfma_f32_16x16x32_bf16(af[mt], bwA[nt], aA[mt][nt], 0, 0, 0);
          aB[mt][nt] = __builtin_amdgcn_mfma_f32_16x16x32_bf16(af[mt], bwB[nt], aB[mt][nt], 0, 0, 0);
        }
    }
    #pragma unroll
    for (int mt = 0; mt < 4; mt++)
      #pragma unroll
      for (int nt = 0; nt < 2; nt++) {
        int c = wv * 32 + nt * 16 + lc;
        #pragma unroll
        for (int r = 0; r < 4; r++) {
          int n = n0 + mt * 16 + qd * 4 + r;
          z1b[(size_t)n * 256 + c] = (__bf16)aA[mt][nt][r];
          z2b[(size_t)n * 256 + c] = (__bf16)aB[mt][nt][r];
        }
      }
  }
}

// ---------------- readout ----------------
__global__ __launch_bounds__(128) void readout_sum_kernel(
    const float* __restrict__ h, const int* __restrict__ batch,
    float* __restrict__ gsum, float* __restrict__ gcnt)
{
  int j = threadIdx.x;
  int n0 = blockIdx.x * 128;
  float acc = 0.f, cacc = 0.f;
  int cur = batch[n0];
  for (int i = 0; i < 128; i++) {
    int b = batch[n0 + i];
    if (b != cur) {
      atomicAdd(&gsum[cur * 128 + j], acc);
      if (j == 0) atomicAdd(&gcnt[cur], cacc);
      acc = 0.f; cacc = 0.f; cur = b;
    }
    acc += h[(size_t)(n0 + i) * 128 + j];
    cacc += 1.f;
  }
  atomicAdd(&gsum[cur * 128 + j], acc);
  if (j == 0) atomicAdd(&gcnt[cur], cacc);
}

__global__ __launch_bounds__(256) void readout_mlp_kernel(
    const float* __restrict__ gsum, const float* __restrict__ gcnt,
    const float* __restrict__ W1, const float* __restrict__ b1,
    const float* __restrict__ W2, const float* __restrict__ b2,
    float* __restrict__ out)
{
  __shared__ float g[8][128];
  __shared__ float hid[8][256];
  int tid = threadIdx.x;
  for (int i = tid; i < 8 * 128; i += 256) {
    int b = i >> 7, c = i & 127;
    g[b][c] = gsum[i] / fmaxf(gcnt[b], 1.0f);
  }
  __syncthreads();
  {
    float bb = b1[tid];
    float a[8];
    #pragma unroll
    for (int b = 0; b < 8; b++) a[b] = bb;
    for (int k = 0; k < 128; k++) {
      float w = W1[k * 256 + tid];
      #pragma unroll
      for (int b = 0; b < 8; b++) a[b] += g[b][k] * w;
    }
    #pragma unroll
    for (int b = 0; b < 8; b++) hid[b][tid] = silu_f(a[b]);
  }
  __syncthreads();
  int j = tid & 63, bg = tid >> 6;
  float a0 = b2[j], a1 = b2[j];
  for (int k = 0; k < 256; k++) {
    float w = W2[k * 64 + j];
    a0 += hid[bg * 2 + 0][k] * w;
    a1 += hid[bg * 2 + 1][k] * w;
  }
  out[(bg * 2 + 0) * 64 + j] = a0;
  out[(bg * 2 + 1) * 64 + j] = a1;
}

extern "C" void kernel_launch(void* const* d_in, const int* in_sizes, int n_in,
                              void* d_out, int out_size, void* d_ws, size_t ws_size,
                              hipStream_t stream) {
  const float* pos   = (const float*)d_in[0];
  const float* xfeat = (const float*)d_in[1];
  const int*   eidx  = (const int*)d_in[2];
  const int*   batch = (const int*)d_in[3];
  const float* eW1 = (const float*)d_in[4];
  const float* eb1 = (const float*)d_in[5];
  const float* eW2 = (const float*)d_in[6];
  const float* eb2 = (const float*)d_in[7];
  const float* mW1 = (const float*)d_in[8];
  const float* mb1 = (const float*)d_in[9];
  const float* mW2 = (const float*)d_in[10];
  const float* mb2 = (const float*)d_in[11];
  const float* uW1 = (const float*)d_in[12];
  const float* ub1 = (const float*)d_in[13];
  const float* uW2 = (const float*)d_in[14];
  const float* ub2 = (const float*)d_in[15];
  const float* rW1 = (const float*)d_in[16];
  const float* rb1 = (const float*)d_in[17];
  const float* rW2 = (const float*)d_in[18];
  const float* rb2 = (const float*)d_in[19];

  const int* srcI = eidx;
  const int* dstI = eidx + NEDGES;

  char* base = (char*)d_ws;
  float* h    = (float*)base;  base += (size_t)NATOMS * 128 * 4;
  float* aggH = (float*)base;  base += (size_t)NATOMS * 256 * 4;
  __bf16* z1b = (__bf16*)base; base += (size_t)NATOMS * 256 * 2;
  __bf16* z2b = (__bf16*)base; base += (size_t)NATOMS * 256 * 2;
  __bf16* hb  = (__bf16*)base; base += (size_t)NATOMS * 128 * 2;
  __bf16* efb = (__bf16*)base; base += (size_t)NEDGES * 16 * 2;
  __bf16* W1at = (__bf16*)base; base += (size_t)NLAYERS * 256 * 128 * 2;
  __bf16* W1bt = (__bf16*)base; base += (size_t)NLAYERS * 256 * 128 * 2;
  __bf16* B2c  = (__bf16*)base; base += (size_t)NLAYERS * 256 * 32 * 2;
  __bf16* uW1ft = (__bf16*)base; base += (size_t)NLAYERS * 256 * 384 * 2;
  __bf16* uW2t = (__bf16*)base; base += (size_t)NLAYERS * 128 * 256 * 2;
  float* b2u  = (float*)base;  base += (size_t)NLAYERS * 256 * 4;
  float* degf = (float*)base;  base += (size_t)NATOMS * 4;
  float* gsum = (float*)base;  base += 8 * 128 * 4;
  float* gcnt = (float*)base;  base += 8 * 4;
  int* counts = (int*)base;    base += (size_t)NATOMS * 4;
  int* cursor = (int*)base;    base += (size_t)NATOMS * 4;
  int* esrc   = (int*)base;    base += (size_t)NEDGES * 4;
  int* edst   = (int*)base;    base += (size_t)NEDGES * 4;

  // counts must be zeroed before front_kernel's hist section
  hipMemsetAsync(counts, 0, NATOMS * sizeof(int), stream);

  // merged front: weight prep + dst histogram + embedding
  front_kernel<<<NB_PREP + NB_HIST + NB_EMB, 256, 0, stream>>>(
      mW1, mW2, uW1, uW2, mb2, W1at, W1bt, B2c, uW1ft, uW2t, b2u,
      dstI, counts, xfeat, eW1, eb1, eW2, eb2, h, hb);

  scan_kernel<<<1, 1024, 0, stream>>>(counts, cursor, degf);
  scatter_rbf_kernel<<<NEDGES / 256, 256, 0, stream>>>(
      srcI, dstI, cursor, pos, esrc, edst, efb);

  // zprep for layer 0 (also zeros aggH)
  zprep_kernel<<<NATOMS / 64, 256, 0, stream>>>(
      hb, mb1, W1at, W1bt, z1b, z2b, aggH);

  for (int l = 0; l < NLAYERS; l++) {
    int ln = (l < NLAYERS - 1) ? (l + 1) : l;
    msg_mfma_kernel<<<NEDGES / TE, 256, 0, stream>>>(
        z1b, z2b, efb, esrc, edst,
        B2c + (size_t)l * 256 * 32, aggH);
    upd_mfma_kernel<<<NATOMS / 64, 512, 0, stream>>>(
        h, hb, aggH, degf,
        uW1ft + (size_t)l * 256 * 384, ub1 + (size_t)l * 256,
        b2u + (size_t)l * 256,
        uW2t + (size_t)l * 128 * 256, ub2 + (size_t)l * 128,
        (l < NLAYERS - 1) ? 1 : 0,
        mb1 + (size_t)ln * 256,
        W1at + (size_t)ln * 256 * 128, W1bt + (size_t)ln * 256 * 128,
        z1b, z2b);
  }

  hipMemsetAsync(gsum, 0, (8 * 128 + 8) * sizeof(float), stream);
  readout_sum_kernel<<<NATOMS / 128, 128, 0, stream>>>(h, batch, gsum, gcnt);
  readout_mlp_kernel<<<1, 256, 0, stream>>>(gsum, gcnt, rW1, rb1, rW2, rb2,
                                            (float*)d_out);
}